// Round 1
// baseline (1342.532 us; speedup 1.0000x reference)
//
#include <hip/hip_runtime.h>
#include <hip/hip_bf16.h>

// Problem constants (shapes fixed by reference)
#define FP 48   // F*P = 4*12 floats per node
#define HID 64
#define NP 12   // periods
#define NF 4    // input feats

// ---------------------------------------------------------------------------
// prep: probs=softmax(att); Mz=Wg_z@Wl_z[:64]; cz=bg_z@Wl_z[:64]+bl_z (same for h);
//       Wc = W1@W2@W3@W4@Wo (64x48); bc = ((((b1@W2+b2)@W3+b3)@W4+b4)@Wo+bo)
// single block, 256 threads
// ---------------------------------------------------------------------------
__global__ __launch_bounds__(256) void prep_kernel(
    const float* __restrict__ att,
    const float* __restrict__ Wg_z, const float* __restrict__ bg_z,
    const float* __restrict__ Wl_z, const float* __restrict__ bl_z,
    const float* __restrict__ Wg_h, const float* __restrict__ bg_h,
    const float* __restrict__ Wl_h, const float* __restrict__ bl_h,
    const float* __restrict__ W1, const float* __restrict__ b1,
    const float* __restrict__ W2, const float* __restrict__ b2,
    const float* __restrict__ W3, const float* __restrict__ b3,
    const float* __restrict__ W4, const float* __restrict__ b4,
    const float* __restrict__ Wo, const float* __restrict__ bo,
    float* __restrict__ probs, float* __restrict__ Mz, float* __restrict__ cz,
    float* __restrict__ Mh, float* __restrict__ ch,
    float* __restrict__ Wc, float* __restrict__ bc)
{
    __shared__ float T[HID * HID];
    __shared__ float U[HID * HID];
    __shared__ float bb[HID];
    __shared__ float bb2[HID];
    const int t = threadIdx.x;

    if (t == 0) {
        float m = att[0];
        for (int p = 1; p < NP; ++p) m = fmaxf(m, att[p]);
        float e[NP]; float s = 0.f;
        for (int p = 0; p < NP; ++p) { e[p] = __expf(att[p] - m); s += e[p]; }
        float inv = 1.f / s;
        for (int p = 0; p < NP; ++p) probs[p] = e[p] * inv;
    }

    // Mz/Mh: 4x64 each; thread t -> (f=t>>6, j=t&63)
    {
        int f = t >> 6, j = t & 63;
        float az = 0.f, ah = 0.f;
        for (int k = 0; k < HID; ++k) {
            az += Wg_z[f * HID + k] * Wl_z[k * HID + j];
            ah += Wg_h[f * HID + k] * Wl_h[k * HID + j];
        }
        Mz[t] = az; Mh[t] = ah;
    }
    if (t < HID) {
        float az = bl_z[t], ah = bl_h[t];
        for (int k = 0; k < HID; ++k) {
            az += bg_z[k] * Wl_z[k * HID + t];
            ah += bg_h[k] * Wl_h[k * HID + t];
        }
        cz[t] = az; ch[t] = ah;
    }

    // stage A: T = W1@W2; bb = b1
    for (int idx = t; idx < HID * HID; idx += 256) {
        int i = idx >> 6, j = idx & 63;
        float a = 0.f;
        for (int k = 0; k < HID; ++k) a += W1[i * HID + k] * W2[k * HID + j];
        T[idx] = a;
    }
    if (t < HID) bb[t] = b1[t];
    __syncthreads();
    // stage B: U = T@W3; bb2 = bb@W2 + b2
    for (int idx = t; idx < HID * HID; idx += 256) {
        int i = idx >> 6, j = idx & 63;
        float a = 0.f;
        for (int k = 0; k < HID; ++k) a += T[i * HID + k] * W3[k * HID + j];
        U[idx] = a;
    }
    if (t < HID) {
        float a = b2[t];
        for (int k = 0; k < HID; ++k) a += bb[k] * W2[k * HID + t];
        bb2[t] = a;
    }
    __syncthreads();
    // stage C: T = U@W4; bb = bb2@W3 + b3
    for (int idx = t; idx < HID * HID; idx += 256) {
        int i = idx >> 6, j = idx & 63;
        float a = 0.f;
        for (int k = 0; k < HID; ++k) a += U[i * HID + k] * W4[k * HID + j];
        T[idx] = a;
    }
    if (t < HID) {
        float a = b3[t];
        for (int k = 0; k < HID; ++k) a += bb2[k] * W3[k * HID + t];
        bb[t] = a;
    }
    __syncthreads();
    // stage D: Wc = T@Wo (64x48); bb2 = bb@W4 + b4
    for (int idx = t; idx < HID * FP; idx += 256) {
        int i = idx / FP, c = idx - i * FP;
        float a = 0.f;
        for (int k = 0; k < HID; ++k) a += T[i * HID + k] * Wo[k * FP + c];
        Wc[idx] = a;
    }
    if (t < HID) {
        float a = b4[t];
        for (int k = 0; k < HID; ++k) a += bb[k] * W4[k * HID + t];
        bb2[t] = a;
    }
    __syncthreads();
    // stage E: bc = bb2@Wo + bo (48)
    if (t < FP) {
        float a = bo[t];
        for (int k = 0; k < HID; ++k) a += bb2[k] * Wo[k * FP + t];
        bc[t] = a;
    }
}

// ---------------------------------------------------------------------------
// degree / normalization
// ---------------------------------------------------------------------------
__global__ void deg_init_kernel(float* __restrict__ deg, int N)
{
    int n = blockIdx.x * blockDim.x + threadIdx.x;
    if (n < N) deg[n] = 1.0f;  // self-loop weight
}

__global__ void deg_acc_kernel(const int* __restrict__ dst, const float* __restrict__ ew,
                               float* __restrict__ deg, int E)
{
    int e = blockIdx.x * blockDim.x + threadIdx.x;
    if (e < E) atomicAdd(&deg[dst[e]], ew[e]);
}

__global__ void dinv_kernel(float* __restrict__ deg, int N)
{
    int n = blockIdx.x * blockDim.x + threadIdx.x;
    if (n < N) {
        float d = deg[n];
        deg[n] = (d > 0.f) ? rsqrtf(d) : 0.f;
    }
}

// y[n*48+c] = x[n*48+c] * dinv[n]^2   (self-loop contribution)
__global__ void y_init_kernel(const float* __restrict__ x, const float* __restrict__ dinv,
                              float* __restrict__ y, int total)
{
    unsigned idx = blockIdx.x * blockDim.x + threadIdx.x;
    if (idx < (unsigned)total) {
        unsigned n = idx / (unsigned)FP;
        float di = dinv[n];
        y[idx] = x[idx] * di * di;
    }
}

// scatter: 12 threads per edge, each does a float4 chunk (4 atomics)
__global__ void scatter_kernel(const float* __restrict__ x,
                               const int* __restrict__ src, const int* __restrict__ dst,
                               const float* __restrict__ ew, const float* __restrict__ dinv,
                               float* __restrict__ y, int E)
{
    unsigned g = blockIdx.x * blockDim.x + threadIdx.x;
    unsigned e = g / 12u;
    unsigned q = g - e * 12u;
    if (e >= (unsigned)E) return;
    int s = src[e], d = dst[e];
    float w = dinv[s] * ew[e] * dinv[d];
    const float4 xv = *reinterpret_cast<const float4*>(x + (size_t)s * FP + q * 4);
    float* yp = y + (size_t)d * FP + q * 4;
    atomicAdd(yp + 0, w * xv.x);
    atomicAdd(yp + 1, w * xv.y);
    atomicAdd(yp + 2, w * xv.z);
    atomicAdd(yp + 3, w * xv.w);
}

// ---------------------------------------------------------------------------
// node kernel: one wave per node
//   lane j holds hidden dim j. For each period p: broadcast the 4 aggregated
//   feats via shfl, compute gz/gh via 4x64 gate mats, accumulate
//   probs[p]*(1-sigmoid)*tanh. Then relu + 64x48 matvec with collapsed head.
// ---------------------------------------------------------------------------
__global__ __launch_bounds__(256) void node_kernel(
    const float* __restrict__ y, const float* __restrict__ probs,
    const float* __restrict__ Mz, const float* __restrict__ cz,
    const float* __restrict__ Mh, const float* __restrict__ ch,
    const float* __restrict__ Wc, const float* __restrict__ bc,
    float* __restrict__ out, int N)
{
    __shared__ float sWc[HID * FP];
    __shared__ float sprobs[NP];
    for (int i = threadIdx.x; i < HID * FP; i += 256) sWc[i] = Wc[i];
    if (threadIdx.x < NP) sprobs[threadIdx.x] = probs[threadIdx.x];
    __syncthreads();

    const int lane = threadIdx.x & 63;
    const int wib  = threadIdx.x >> 6;
    const int gwave = blockIdx.x * 4 + wib;
    const int nwaves = gridDim.x * 4;

    // per-lane gate params
    const float mz0 = Mz[lane], mz1 = Mz[64 + lane], mz2 = Mz[128 + lane], mz3 = Mz[192 + lane];
    const float mh0 = Mh[lane], mh1 = Mh[64 + lane], mh2 = Mh[128 + lane], mh3 = Mh[192 + lane];
    const float czv = cz[lane], chv = ch[lane];
    const int   c   = (lane < FP) ? lane : 0;   // safe index for lanes >= 48
    const float bcv = bc[c];
    float pr[NP];
    #pragma unroll
    for (int p = 0; p < NP; ++p) pr[p] = sprobs[p];

    for (int n = gwave; n < N; n += nwaves) {
        float yv = (lane < FP) ? y[(size_t)n * FP + lane] : 0.f;
        float hacc = 0.f;
        #pragma unroll
        for (int p = 0; p < NP; ++p) {
            float v0 = __shfl(yv, p,      64);
            float v1 = __shfl(yv, p + 12, 64);
            float v2 = __shfl(yv, p + 24, 64);
            float v3 = __shfl(yv, p + 36, 64);
            float az = czv + v0 * mz0 + v1 * mz1 + v2 * mz2 + v3 * mz3;
            float ah = chv + v0 * mh0 + v1 * mh1 + v2 * mh2 + v3 * mh3;
            float zz = 1.f / (1.f + __expf(-az));
            float th = tanhf(ah);
            hacc += pr[p] * (1.f - zz) * th;
        }
        hacc = fmaxf(hacc, 0.f);  // relu on the summed hidden state

        // out[n, c] = bc[c] + sum_i h[i] * Wc[i*48+c]
        float o = bcv;
        #pragma unroll 16
        for (int i = 0; i < HID; ++i) {
            float hi = __shfl(hacc, i, 64);
            o += hi * sWc[i * FP + c];
        }
        if (lane < FP) out[(size_t)n * FP + lane] = o;
    }
}

// ---------------------------------------------------------------------------
extern "C" void kernel_launch(void* const* d_in, const int* in_sizes, int n_in,
                              void* d_out, int out_size, void* d_ws, size_t ws_size,
                              hipStream_t stream)
{
    const int N = in_sizes[0] / FP;   // 50000
    const int E = in_sizes[1] / 2;    // 1.6M

    const float* x    = (const float*)d_in[0];
    const int*   ei   = (const int*)d_in[1];
    const float* ew   = (const float*)d_in[2];
    const float* att  = (const float*)d_in[3];
    const float* Wg_z = (const float*)d_in[4];
    const float* bg_z = (const float*)d_in[5];
    const float* Wl_z = (const float*)d_in[6];
    const float* bl_z = (const float*)d_in[7];
    // d_in[8..11] = r-gate params: provably unused (H=0 => Hz*r = 0)
    const float* Wg_h = (const float*)d_in[12];
    const float* bg_h = (const float*)d_in[13];
    const float* Wl_h = (const float*)d_in[14];
    const float* bl_h = (const float*)d_in[15];
    const float* W1 = (const float*)d_in[16]; const float* b1 = (const float*)d_in[17];
    const float* W2 = (const float*)d_in[18]; const float* b2 = (const float*)d_in[19];
    const float* W3 = (const float*)d_in[20]; const float* b3 = (const float*)d_in[21];
    const float* W4 = (const float*)d_in[22]; const float* b4 = (const float*)d_in[23];
    const float* Wo = (const float*)d_in[24]; const float* bo = (const float*)d_in[25];

    const int* srcp = ei;
    const int* dstp = ei + E;

    // workspace layout (floats)
    float* ws    = (float*)d_ws;
    float* deg   = ws;                       // N (becomes dinv in-place)
    float* y     = deg + N;                  // N*48
    float* probs = y + (size_t)N * FP;       // 12 (pad to 16)
    float* Mz    = probs + 16;               // 256
    float* cz    = Mz + 256;                 // 64
    float* Mh    = cz + 64;                  // 256
    float* ch    = Mh + 256;                 // 64
    float* Wc    = ch + 64;                  // 3072
    float* bc    = Wc + HID * FP;            // 48

    prep_kernel<<<1, 256, 0, stream>>>(att, Wg_z, bg_z, Wl_z, bl_z, Wg_h, bg_h, Wl_h, bl_h,
                                       W1, b1, W2, b2, W3, b3, W4, b4, Wo, bo,
                                       probs, Mz, cz, Mh, ch, Wc, bc);

    deg_init_kernel<<<(N + 255) / 256, 256, 0, stream>>>(deg, N);
    deg_acc_kernel<<<(E + 255) / 256, 256, 0, stream>>>(dstp, ew, deg, E);
    dinv_kernel<<<(N + 255) / 256, 256, 0, stream>>>(deg, N);

    const int totY = N * FP;
    y_init_kernel<<<(totY + 255) / 256, 256, 0, stream>>>(x, deg, y, totY);

    const long long scatThreads = (long long)E * 12;
    scatter_kernel<<<(int)((scatThreads + 255) / 256), 256, 0, stream>>>(x, srcp, dstp, ew, deg, y, E);

    node_kernel<<<2048, 256, 0, stream>>>(y, probs, Mz, cz, Mh, ch, Wc, bc, (float*)d_out, N);
}

// Round 2
// 797.144 us; speedup vs baseline: 1.6842x; 1.6842x over previous
//
#include <hip/hip_runtime.h>
#include <hip/hip_bf16.h>

// Problem constants (shapes fixed by reference)
#define FP 48   // F*P = 4*12 floats per node
#define HID 64
#define NP 12   // periods
#define NF 4    // input feats

// ---------------------------------------------------------------------------
// prep: probs=softmax(att); Mz=Wg_z@Wl_z[:64]; cz=bg_z@Wl_z[:64]+bl_z (same for h);
//       Wc = W1@W2@W3@W4@Wo (64x48); bc = ((((b1@W2+b2)@W3+b3)@W4+b4)@Wo+bo)
// single block, 256 threads. r-gate params provably unused (H=0 => Hz*r = 0).
// ---------------------------------------------------------------------------
__global__ __launch_bounds__(256) void prep_kernel(
    const float* __restrict__ att,
    const float* __restrict__ Wg_z, const float* __restrict__ bg_z,
    const float* __restrict__ Wl_z, const float* __restrict__ bl_z,
    const float* __restrict__ Wg_h, const float* __restrict__ bg_h,
    const float* __restrict__ Wl_h, const float* __restrict__ bl_h,
    const float* __restrict__ W1, const float* __restrict__ b1,
    const float* __restrict__ W2, const float* __restrict__ b2,
    const float* __restrict__ W3, const float* __restrict__ b3,
    const float* __restrict__ W4, const float* __restrict__ b4,
    const float* __restrict__ Wo, const float* __restrict__ bo,
    float* __restrict__ probs, float* __restrict__ Mz, float* __restrict__ cz,
    float* __restrict__ Mh, float* __restrict__ ch,
    float* __restrict__ Wc, float* __restrict__ bc)
{
    __shared__ float T[HID * HID];
    __shared__ float U[HID * HID];
    __shared__ float bb[HID];
    __shared__ float bb2[HID];
    const int t = threadIdx.x;

    if (t == 0) {
        float m = att[0];
        for (int p = 1; p < NP; ++p) m = fmaxf(m, att[p]);
        float e[NP]; float s = 0.f;
        for (int p = 0; p < NP; ++p) { e[p] = __expf(att[p] - m); s += e[p]; }
        float inv = 1.f / s;
        for (int p = 0; p < NP; ++p) probs[p] = e[p] * inv;
    }

    // Mz/Mh: 4x64 each; thread t -> (f=t>>6, j=t&63)
    {
        int f = t >> 6, j = t & 63;
        float az = 0.f, ah = 0.f;
        for (int k = 0; k < HID; ++k) {
            az += Wg_z[f * HID + k] * Wl_z[k * HID + j];
            ah += Wg_h[f * HID + k] * Wl_h[k * HID + j];
        }
        Mz[t] = az; Mh[t] = ah;
    }
    if (t < HID) {
        float az = bl_z[t], ah = bl_h[t];
        for (int k = 0; k < HID; ++k) {
            az += bg_z[k] * Wl_z[k * HID + t];
            ah += bg_h[k] * Wl_h[k * HID + t];
        }
        cz[t] = az; ch[t] = ah;
    }

    // stage A: T = W1@W2; bb = b1
    for (int idx = t; idx < HID * HID; idx += 256) {
        int i = idx >> 6, j = idx & 63;
        float a = 0.f;
        for (int k = 0; k < HID; ++k) a += W1[i * HID + k] * W2[k * HID + j];
        T[idx] = a;
    }
    if (t < HID) bb[t] = b1[t];
    __syncthreads();
    // stage B: U = T@W3; bb2 = bb@W2 + b2
    for (int idx = t; idx < HID * HID; idx += 256) {
        int i = idx >> 6, j = idx & 63;
        float a = 0.f;
        for (int k = 0; k < HID; ++k) a += T[i * HID + k] * W3[k * HID + j];
        U[idx] = a;
    }
    if (t < HID) {
        float a = b2[t];
        for (int k = 0; k < HID; ++k) a += bb[k] * W2[k * HID + t];
        bb2[t] = a;
    }
    __syncthreads();
    // stage C: T = U@W4; bb = bb2@W3 + b3
    for (int idx = t; idx < HID * HID; idx += 256) {
        int i = idx >> 6, j = idx & 63;
        float a = 0.f;
        for (int k = 0; k < HID; ++k) a += U[i * HID + k] * W4[k * HID + j];
        T[idx] = a;
    }
    if (t < HID) {
        float a = b3[t];
        for (int k = 0; k < HID; ++k) a += bb2[k] * W3[k * HID + t];
        bb[t] = a;
    }
    __syncthreads();
    // stage D: Wc = T@Wo (64x48); bb2 = bb@W4 + b4
    for (int idx = t; idx < HID * FP; idx += 256) {
        int i = idx / FP, c = idx - i * FP;
        float a = 0.f;
        for (int k = 0; k < HID; ++k) a += T[i * HID + k] * Wo[k * FP + c];
        Wc[idx] = a;
    }
    if (t < HID) {
        float a = b4[t];
        for (int k = 0; k < HID; ++k) a += bb[k] * W4[k * HID + t];
        bb2[t] = a;
    }
    __syncthreads();
    // stage E: bc = bb2@Wo + bo (48)
    if (t < FP) {
        float a = bo[t];
        for (int k = 0; k < HID; ++k) a += bb2[k] * Wo[k * FP + t];
        bc[t] = a;
    }
}

// ---------------------------------------------------------------------------
// CSR construction
// ---------------------------------------------------------------------------
__global__ void init_kernel(float* __restrict__ deg, int* __restrict__ count, int N)
{
    int n = blockIdx.x * blockDim.x + threadIdx.x;
    if (n < N) { deg[n] = 1.0f; count[n] = 0; }   // self-loop weight 1
}

__global__ void hist_kernel(const int* __restrict__ dst, const float* __restrict__ ew,
                            float* __restrict__ deg, int* __restrict__ count, int E)
{
    int e = blockIdx.x * blockDim.x + threadIdx.x;
    if (e < E) {
        int d = dst[e];
        atomicAdd(&count[d], 1);
        atomicAdd(&deg[d], ew[e]);
    }
}

__global__ void dinv_kernel(float* __restrict__ deg, int N)
{
    int n = blockIdx.x * blockDim.x + threadIdx.x;
    if (n < N) {
        float d = deg[n];
        deg[n] = (d > 0.f) ? rsqrtf(d) : 0.f;
    }
}

// single-block exclusive scan of count[0..N) -> rowstart[0..N], cursor[0..N)
__global__ __launch_bounds__(1024) void scan_kernel(const int* __restrict__ count,
                                                    int* __restrict__ rowstart,
                                                    int* __restrict__ cursor, int N)
{
    __shared__ int sums[1024];
    const int t = threadIdx.x;
    const int C = (N + 1023) / 1024;
    const int lo = t * C;
    const int hi = min(lo + C, N);

    int s = 0;
    for (int i = lo; i < hi; ++i) s += count[i];
    sums[t] = s;
    __syncthreads();
    // Hillis-Steele inclusive scan over 1024 thread sums
    for (int off = 1; off < 1024; off <<= 1) {
        int v = (t >= off) ? sums[t - off] : 0;
        __syncthreads();
        sums[t] += v;
        __syncthreads();
    }
    int run = sums[t] - s;   // exclusive prefix of this thread's chunk
    for (int i = lo; i < hi; ++i) {
        rowstart[i] = run;
        cursor[i]   = run;
        run += count[i];
    }
    if (t == 1023) rowstart[N] = sums[1023];
}

// scatter edges into CSR slots; pack {src, w = dinv[src]*ew} into 8B
__global__ void fill_kernel(const int* __restrict__ src, const int* __restrict__ dst,
                            const float* __restrict__ ew, const float* __restrict__ dinv,
                            int* __restrict__ cursor, int2* __restrict__ edges, int E)
{
    int e = blockIdx.x * blockDim.x + threadIdx.x;
    if (e < E) {
        int s = src[e], d = dst[e];
        int pos = atomicAdd(&cursor[d], 1);
        int2 pk;
        pk.x = s;
        pk.y = __float_as_int(dinv[s] * ew[e]);
        edges[pos] = pk;
    }
}

// ---------------------------------------------------------------------------
// fused gather + node kernel: one wave per dst node.
// lane j (<48) accumulates aggregated feature j over the node's CSR row,
// folds in self-loop + dinv[dst], then runs the gate/period loop and the
// collapsed 64x48 head matvec, writing out directly (no y round-trip).
// ---------------------------------------------------------------------------
__global__ __launch_bounds__(256) void gather_node_kernel(
    const float* __restrict__ x, const int* __restrict__ rowstart,
    const int2* __restrict__ edges, const float* __restrict__ dinv,
    const float* __restrict__ probs,
    const float* __restrict__ Mz, const float* __restrict__ cz,
    const float* __restrict__ Mh, const float* __restrict__ ch,
    const float* __restrict__ Wc, const float* __restrict__ bc,
    float* __restrict__ out, int N)
{
    __shared__ float sWc[HID * FP];
    __shared__ float sprobs[NP];
    for (int i = threadIdx.x; i < HID * FP; i += 256) sWc[i] = Wc[i];
    if (threadIdx.x < NP) sprobs[threadIdx.x] = probs[threadIdx.x];
    __syncthreads();

    const int lane = threadIdx.x & 63;
    const int wib  = threadIdx.x >> 6;
    const int n    = blockIdx.x * 4 + wib;
    if (n >= N) return;

    // per-lane gate params
    const float mz0 = Mz[lane], mz1 = Mz[64 + lane], mz2 = Mz[128 + lane], mz3 = Mz[192 + lane];
    const float mh0 = Mh[lane], mh1 = Mh[64 + lane], mh2 = Mh[128 + lane], mh3 = Mh[192 + lane];
    const float czv = cz[lane], chv = ch[lane];
    const int   c   = (lane < FP) ? lane : 0;
    const float bcv = bc[c];

    // ---- gather phase: acc = sum_e w_e * x[src_e, lane] ----
    const int beg = rowstart[n];
    const int end = rowstart[n + 1];
    float acc = 0.f;
    int e = beg;
    for (; e + 1 < end; e += 2) {
        int2 p0 = edges[e];
        int2 p1 = edges[e + 1];
        float x0 = (lane < FP) ? x[(size_t)p0.x * FP + lane] : 0.f;
        float x1 = (lane < FP) ? x[(size_t)p1.x * FP + lane] : 0.f;
        acc += __int_as_float(p0.y) * x0;
        acc += __int_as_float(p1.y) * x1;
    }
    if (e < end) {
        int2 p0 = edges[e];
        float x0 = (lane < FP) ? x[(size_t)p0.x * FP + lane] : 0.f;
        acc += __int_as_float(p0.y) * x0;
    }
    const float di = dinv[n];
    float xself = (lane < FP) ? x[(size_t)n * FP + lane] : 0.f;
    float yv = di * acc + di * di * xself;   // aggregated features, lane-resident

    // ---- node phase ----
    float hacc = 0.f;
    #pragma unroll
    for (int p = 0; p < NP; ++p) {
        float v0 = __shfl(yv, p,      64);
        float v1 = __shfl(yv, p + 12, 64);
        float v2 = __shfl(yv, p + 24, 64);
        float v3 = __shfl(yv, p + 36, 64);
        float az = czv + v0 * mz0 + v1 * mz1 + v2 * mz2 + v3 * mz3;
        float ah = chv + v0 * mh0 + v1 * mh1 + v2 * mh2 + v3 * mh3;
        float zz = 1.f / (1.f + __expf(-az));
        float th = tanhf(ah);
        hacc += sprobs[p] * (1.f - zz) * th;
    }
    hacc = fmaxf(hacc, 0.f);

    float o = bcv;
    #pragma unroll 16
    for (int i = 0; i < HID; ++i) {
        float hi = __shfl(hacc, i, 64);
        o += hi * sWc[i * FP + c];
    }
    if (lane < FP) out[(size_t)n * FP + lane] = o;
}

// ---------------------------------------------------------------------------
extern "C" void kernel_launch(void* const* d_in, const int* in_sizes, int n_in,
                              void* d_out, int out_size, void* d_ws, size_t ws_size,
                              hipStream_t stream)
{
    const int N = in_sizes[0] / FP;   // 50000
    const int E = in_sizes[1] / 2;    // 1.6M

    const float* x    = (const float*)d_in[0];
    const int*   ei   = (const int*)d_in[1];
    const float* ew   = (const float*)d_in[2];
    const float* att  = (const float*)d_in[3];
    const float* Wg_z = (const float*)d_in[4];
    const float* bg_z = (const float*)d_in[5];
    const float* Wl_z = (const float*)d_in[6];
    const float* bl_z = (const float*)d_in[7];
    // d_in[8..11] = r-gate params: unused (H=0 => Hz*r = 0)
    const float* Wg_h = (const float*)d_in[12];
    const float* bg_h = (const float*)d_in[13];
    const float* Wl_h = (const float*)d_in[14];
    const float* bl_h = (const float*)d_in[15];
    const float* W1 = (const float*)d_in[16]; const float* b1 = (const float*)d_in[17];
    const float* W2 = (const float*)d_in[18]; const float* b2 = (const float*)d_in[19];
    const float* W3 = (const float*)d_in[20]; const float* b3 = (const float*)d_in[21];
    const float* W4 = (const float*)d_in[22]; const float* b4 = (const float*)d_in[23];
    const float* Wo = (const float*)d_in[24]; const float* bo = (const float*)d_in[25];

    const int* srcp = ei;
    const int* dstp = ei + E;

    // workspace layout (4B words; edges first for 8B alignment)
    int2*  edges   = (int2*)d_ws;                    // E int2 (8B each)
    float* deg     = (float*)(edges + E);            // N floats (becomes dinv)
    int*   count   = (int*)(deg + N);                // N
    int*   rowstart= count + N;                      // N+1
    int*   cursor  = rowstart + N + 1;               // N
    float* probs   = (float*)(cursor + N);           // 16
    float* Mz      = probs + 16;                     // 256
    float* cz      = Mz + 256;                       // 64
    float* Mh      = cz + 64;                        // 256
    float* ch      = Mh + 256;                       // 64
    float* Wc      = ch + 64;                        // 3072
    float* bc      = Wc + HID * FP;                  // 48

    prep_kernel<<<1, 256, 0, stream>>>(att, Wg_z, bg_z, Wl_z, bl_z, Wg_h, bg_h, Wl_h, bl_h,
                                       W1, b1, W2, b2, W3, b3, W4, b4, Wo, bo,
                                       probs, Mz, cz, Mh, ch, Wc, bc);

    init_kernel<<<(N + 255) / 256, 256, 0, stream>>>(deg, count, N);
    hist_kernel<<<(E + 255) / 256, 256, 0, stream>>>(dstp, ew, deg, count, E);
    dinv_kernel<<<(N + 255) / 256, 256, 0, stream>>>(deg, N);
    scan_kernel<<<1, 1024, 0, stream>>>(count, rowstart, cursor, N);
    fill_kernel<<<(E + 255) / 256, 256, 0, stream>>>(srcp, dstp, ew, deg, cursor, edges, E);

    gather_node_kernel<<<(N + 3) / 4, 256, 0, stream>>>(x, rowstart, edges, deg,
                                                        probs, Mz, cz, Mh, ch, Wc, bc,
                                                        (float*)d_out, N);
}

// Round 3
// 583.132 us; speedup vs baseline: 2.3023x; 1.3670x over previous
//
#include <hip/hip_runtime.h>
#include <hip/hip_bf16.h>

// Problem constants (shapes fixed by reference)
#define FP 48   // F*P = 4*12 floats per node
#define HID 64
#define NP 12   // periods
#define NF 4    // input feats
#define SCAN_B 1024

// ---------------------------------------------------------------------------
// prep: probs=softmax(att); Mz=Wg_z@Wl_z[:64]; cz=bg_z@Wl_z[:64]+bl_z (same for h);
//       Wc = W1@W2@W3@W4@Wo (64x48); bc = ((((b1@W2+b2)@W3+b3)@W4+b4)@Wo+bo)
// r-gate params provably unused (H=0 => Hz*r = 0).
// ---------------------------------------------------------------------------
__global__ __launch_bounds__(256) void prep_kernel(
    const float* __restrict__ att,
    const float* __restrict__ Wg_z, const float* __restrict__ bg_z,
    const float* __restrict__ Wl_z, const float* __restrict__ bl_z,
    const float* __restrict__ Wg_h, const float* __restrict__ bg_h,
    const float* __restrict__ Wl_h, const float* __restrict__ bl_h,
    const float* __restrict__ W1, const float* __restrict__ b1,
    const float* __restrict__ W2, const float* __restrict__ b2,
    const float* __restrict__ W3, const float* __restrict__ b3,
    const float* __restrict__ W4, const float* __restrict__ b4,
    const float* __restrict__ Wo, const float* __restrict__ bo,
    float* __restrict__ probs, float* __restrict__ Mz, float* __restrict__ cz,
    float* __restrict__ Mh, float* __restrict__ ch,
    float* __restrict__ Wc, float* __restrict__ bc)
{
    __shared__ float T[HID * HID];
    __shared__ float U[HID * HID];
    __shared__ float bb[HID];
    __shared__ float bb2[HID];
    const int t = threadIdx.x;

    if (t == 0) {
        float m = att[0];
        for (int p = 1; p < NP; ++p) m = fmaxf(m, att[p]);
        float e[NP]; float s = 0.f;
        for (int p = 0; p < NP; ++p) { e[p] = __expf(att[p] - m); s += e[p]; }
        float inv = 1.f / s;
        for (int p = 0; p < NP; ++p) probs[p] = e[p] * inv;
    }

    {
        int f = t >> 6, j = t & 63;
        float az = 0.f, ah = 0.f;
        for (int k = 0; k < HID; ++k) {
            az += Wg_z[f * HID + k] * Wl_z[k * HID + j];
            ah += Wg_h[f * HID + k] * Wl_h[k * HID + j];
        }
        Mz[t] = az; Mh[t] = ah;
    }
    if (t < HID) {
        float az = bl_z[t], ah = bl_h[t];
        for (int k = 0; k < HID; ++k) {
            az += bg_z[k] * Wl_z[k * HID + t];
            ah += bg_h[k] * Wl_h[k * HID + t];
        }
        cz[t] = az; ch[t] = ah;
    }

    for (int idx = t; idx < HID * HID; idx += 256) {
        int i = idx >> 6, j = idx & 63;
        float a = 0.f;
        for (int k = 0; k < HID; ++k) a += W1[i * HID + k] * W2[k * HID + j];
        T[idx] = a;
    }
    if (t < HID) bb[t] = b1[t];
    __syncthreads();
    for (int idx = t; idx < HID * HID; idx += 256) {
        int i = idx >> 6, j = idx & 63;
        float a = 0.f;
        for (int k = 0; k < HID; ++k) a += T[i * HID + k] * W3[k * HID + j];
        U[idx] = a;
    }
    if (t < HID) {
        float a = b2[t];
        for (int k = 0; k < HID; ++k) a += bb[k] * W2[k * HID + t];
        bb2[t] = a;
    }
    __syncthreads();
    for (int idx = t; idx < HID * HID; idx += 256) {
        int i = idx >> 6, j = idx & 63;
        float a = 0.f;
        for (int k = 0; k < HID; ++k) a += U[i * HID + k] * W4[k * HID + j];
        T[idx] = a;
    }
    if (t < HID) {
        float a = b3[t];
        for (int k = 0; k < HID; ++k) a += bb2[k] * W3[k * HID + t];
        bb[t] = a;
    }
    __syncthreads();
    for (int idx = t; idx < HID * FP; idx += 256) {
        int i = idx / FP, c = idx - i * FP;
        float a = 0.f;
        for (int k = 0; k < HID; ++k) a += T[i * HID + k] * Wo[k * FP + c];
        Wc[idx] = a;
    }
    if (t < HID) {
        float a = b4[t];
        for (int k = 0; k < HID; ++k) a += bb[k] * W4[k * HID + t];
        bb2[t] = a;
    }
    __syncthreads();
    if (t < FP) {
        float a = bo[t];
        for (int k = 0; k < HID; ++k) a += bb2[k] * Wo[k * FP + t];
        bc[t] = a;
    }
}

// ---------------------------------------------------------------------------
// CSR construction
// ---------------------------------------------------------------------------
__global__ void init_kernel(float* __restrict__ deg, int* __restrict__ count, int N)
{
    int n = blockIdx.x * blockDim.x + threadIdx.x;
    if (n < N) { deg[n] = 1.0f; count[n] = 0; }   // self-loop weight 1
}

__global__ void hist_kernel(const int* __restrict__ dst, const float* __restrict__ ew,
                            float* __restrict__ deg, int* __restrict__ count, int E)
{
    int e = blockIdx.x * blockDim.x + threadIdx.x;
    if (e < E) {
        int d = dst[e];
        atomicAdd(&count[d], 1);
        atomicAdd(&deg[d], ew[e]);
    }
}

// phase A: per-block sums of count (coalesced)
__global__ __launch_bounds__(SCAN_B) void scanA_kernel(const int* __restrict__ count,
                                                       int* __restrict__ partials, int N)
{
    __shared__ int red[SCAN_B];
    const int t = threadIdx.x;
    const int idx = blockIdx.x * SCAN_B + t;
    red[t] = (idx < N) ? count[idx] : 0;
    __syncthreads();
    for (int s = SCAN_B / 2; s > 0; s >>= 1) {
        if (t < s) red[t] += red[t + s];
        __syncthreads();
    }
    if (t == 0) partials[blockIdx.x] = red[0];
}

// phase B: tiny exclusive scan of block partials
__global__ void scanB_kernel(const int* __restrict__ partials, int* __restrict__ blockoff, int NB)
{
    if (threadIdx.x == 0) {
        int run = 0;
        for (int i = 0; i < NB; ++i) { blockoff[i] = run; run += partials[i]; }
    }
}

// phase C: per-block Hillis-Steele scan + offset; fuses dinv (deg -> rsqrt(deg))
__global__ __launch_bounds__(SCAN_B) void scanC_kernel(const int* __restrict__ count,
                                                       const int* __restrict__ blockoff,
                                                       int* __restrict__ rowstart,
                                                       int* __restrict__ cursor,
                                                       float* __restrict__ deg, int N)
{
    __shared__ int sdata[SCAN_B];
    const int t = threadIdx.x;
    const int idx = blockIdx.x * SCAN_B + t;
    const int v = (idx < N) ? count[idx] : 0;
    sdata[t] = v;
    __syncthreads();
    for (int off = 1; off < SCAN_B; off <<= 1) {
        int tmp = (t >= off) ? sdata[t - off] : 0;
        __syncthreads();
        sdata[t] += tmp;
        __syncthreads();
    }
    const int incl = sdata[t];
    const int off0 = blockoff[blockIdx.x];
    if (idx < N) {
        int e = off0 + incl - v;
        rowstart[idx] = e;
        cursor[idx]   = e;
        float d = deg[idx];
        deg[idx] = (d > 0.f) ? rsqrtf(d) : 0.f;
    }
    if (idx == N - 1) rowstart[N] = off0 + incl;
}

// scatter edges into CSR slots; pack {src, w = dinv[src]*ew} into 8B
__global__ void fill_kernel(const int* __restrict__ src, const int* __restrict__ dst,
                            const float* __restrict__ ew, const float* __restrict__ dinv,
                            int* __restrict__ cursor, int2* __restrict__ edges, int E)
{
    int e = blockIdx.x * blockDim.x + threadIdx.x;
    if (e < E) {
        int s = src[e], d = dst[e];
        int pos = atomicAdd(&cursor[d], 1);
        int2 pk;
        pk.x = s;
        pk.y = __float_as_int(dinv[s] * ew[e]);
        edges[pos] = pk;
    }
}

// ---------------------------------------------------------------------------
// fused gather + node kernel: one wave per dst node.
// Gather layout: lane = slot*16 + q; 4 edge slots, q<12 lanes load the slot's
// x row as float4 (12*4 = 48 floats). 4 independent row loads in flight per
// iteration (x2 unroll). Cross-slot shfl_xor reduce, then redistribute to
// lane=feature layout for the gate/head phase.
// ---------------------------------------------------------------------------
__global__ __launch_bounds__(256) void gather_node_kernel(
    const float* __restrict__ x, const int* __restrict__ rowstart,
    const int2* __restrict__ edges, const float* __restrict__ dinv,
    const float* __restrict__ probs,
    const float* __restrict__ Mz, const float* __restrict__ cz,
    const float* __restrict__ Mh, const float* __restrict__ ch,
    const float* __restrict__ Wc, const float* __restrict__ bc,
    float* __restrict__ out, int N)
{
    __shared__ float sWc[HID * FP];
    __shared__ float sprobs[NP];
    for (int i = threadIdx.x; i < HID * FP; i += 256) sWc[i] = Wc[i];
    if (threadIdx.x < NP) sprobs[threadIdx.x] = probs[threadIdx.x];
    __syncthreads();

    const int lane = threadIdx.x & 63;
    const int wib  = threadIdx.x >> 6;
    const int n    = blockIdx.x * 4 + wib;
    if (n >= N) return;

    const int q    = lane & 15;      // float4 index within row
    const int slot = lane >> 4;      // which of 4 edges this iteration
    const bool act = (q < 12);       // 12 float4s cover 48 floats

    const int beg = rowstart[n];
    const int end = rowstart[n + 1];

    float4 acc = make_float4(0.f, 0.f, 0.f, 0.f);
    #pragma unroll 2
    for (int e0 = beg; e0 < end; e0 += 4) {
        int e = e0 + slot;
        float w = 0.f; int s = 0;
        if (e < end) {
            int2 pk = edges[e];
            s = pk.x;
            w = __int_as_float(pk.y);
        }
        float4 xv = make_float4(0.f, 0.f, 0.f, 0.f);
        if (act) xv = *reinterpret_cast<const float4*>(x + (size_t)s * FP + q * 4);
        acc.x += w * xv.x; acc.y += w * xv.y; acc.z += w * xv.z; acc.w += w * xv.w;
    }

    // reduce across the 4 slots (lanes differing in bits 4,5)
    acc.x += __shfl_xor(acc.x, 16, 64); acc.y += __shfl_xor(acc.y, 16, 64);
    acc.z += __shfl_xor(acc.z, 16, 64); acc.w += __shfl_xor(acc.w, 16, 64);
    acc.x += __shfl_xor(acc.x, 32, 64); acc.y += __shfl_xor(acc.y, 32, 64);
    acc.z += __shfl_xor(acc.z, 32, 64); acc.w += __shfl_xor(acc.w, 32, 64);

    // self loop + symmetric norm
    const float di = dinv[n];
    float4 xs = make_float4(0.f, 0.f, 0.f, 0.f);
    if (act) xs = *reinterpret_cast<const float4*>(x + (size_t)n * FP + q * 4);
    float4 y4;
    y4.x = di * acc.x + di * di * xs.x;
    y4.y = di * acc.y + di * di * xs.y;
    y4.z = di * acc.z + di * di * xs.z;
    y4.w = di * acc.w + di * di * xs.w;

    // redistribute: lane f (<48) takes component (f&3) of y4 from lane f>>2
    const int srcl = lane >> 2;
    float a0 = __shfl(y4.x, srcl, 64);
    float a1 = __shfl(y4.y, srcl, 64);
    float a2 = __shfl(y4.z, srcl, 64);
    float a3 = __shfl(y4.w, srcl, 64);
    const int r = lane & 3;
    float yv = (r == 0) ? a0 : (r == 1) ? a1 : (r == 2) ? a2 : a3;

    // ---- node phase (lane = hidden dim) ----
    const float mz0 = Mz[lane], mz1 = Mz[64 + lane], mz2 = Mz[128 + lane], mz3 = Mz[192 + lane];
    const float mh0 = Mh[lane], mh1 = Mh[64 + lane], mh2 = Mh[128 + lane], mh3 = Mh[192 + lane];
    const float czv = cz[lane], chv = ch[lane];
    const int   c   = (lane < FP) ? lane : 0;
    const float bcv = bc[c];

    float hacc = 0.f;
    #pragma unroll
    for (int p = 0; p < NP; ++p) {
        float v0 = __shfl(yv, p,      64);
        float v1 = __shfl(yv, p + 12, 64);
        float v2 = __shfl(yv, p + 24, 64);
        float v3 = __shfl(yv, p + 36, 64);
        float az = czv + v0 * mz0 + v1 * mz1 + v2 * mz2 + v3 * mz3;
        float ah = chv + v0 * mh0 + v1 * mh1 + v2 * mh2 + v3 * mh3;
        float zz = 1.f / (1.f + __expf(-az));
        float th = tanhf(ah);
        hacc += sprobs[p] * (1.f - zz) * th;
    }
    hacc = fmaxf(hacc, 0.f);

    float o = bcv;
    #pragma unroll 16
    for (int i = 0; i < HID; ++i) {
        float hi = __shfl(hacc, i, 64);
        o += hi * sWc[i * FP + c];
    }
    if (lane < FP) out[(size_t)n * FP + lane] = o;
}

// ---------------------------------------------------------------------------
extern "C" void kernel_launch(void* const* d_in, const int* in_sizes, int n_in,
                              void* d_out, int out_size, void* d_ws, size_t ws_size,
                              hipStream_t stream)
{
    const int N = in_sizes[0] / FP;   // 50000
    const int E = in_sizes[1] / 2;    // 1.6M
    const int NB = (N + SCAN_B - 1) / SCAN_B;

    const float* x    = (const float*)d_in[0];
    const int*   ei   = (const int*)d_in[1];
    const float* ew   = (const float*)d_in[2];
    const float* att  = (const float*)d_in[3];
    const float* Wg_z = (const float*)d_in[4];
    const float* bg_z = (const float*)d_in[5];
    const float* Wl_z = (const float*)d_in[6];
    const float* bl_z = (const float*)d_in[7];
    // d_in[8..11] = r-gate params: unused (H=0 => Hz*r = 0)
    const float* Wg_h = (const float*)d_in[12];
    const float* bg_h = (const float*)d_in[13];
    const float* Wl_h = (const float*)d_in[14];
    const float* bl_h = (const float*)d_in[15];
    const float* W1 = (const float*)d_in[16]; const float* b1 = (const float*)d_in[17];
    const float* W2 = (const float*)d_in[18]; const float* b2 = (const float*)d_in[19];
    const float* W3 = (const float*)d_in[20]; const float* b3 = (const float*)d_in[21];
    const float* W4 = (const float*)d_in[22]; const float* b4 = (const float*)d_in[23];
    const float* Wo = (const float*)d_in[24]; const float* bo = (const float*)d_in[25];

    const int* srcp = ei;
    const int* dstp = ei + E;

    // workspace layout (edges first for 8B alignment)
    int2*  edges    = (int2*)d_ws;                   // E int2
    float* deg      = (float*)(edges + E);           // N (becomes dinv)
    int*   count    = (int*)(deg + N);               // N
    int*   rowstart = count + N;                     // N+1
    int*   cursor   = rowstart + N + 1;              // N
    int*   partials = cursor + N;                    // NB (<=64)
    int*   blockoff = partials + 64;                 // NB (<=64)
    float* probs    = (float*)(blockoff + 64);       // 16
    float* Mz       = probs + 16;                    // 256
    float* cz       = Mz + 256;                      // 64
    float* Mh       = cz + 64;                       // 256
    float* ch       = Mh + 256;                      // 64
    float* Wc       = ch + 64;                       // 3072
    float* bc       = Wc + HID * FP;                 // 48

    prep_kernel<<<1, 256, 0, stream>>>(att, Wg_z, bg_z, Wl_z, bl_z, Wg_h, bg_h, Wl_h, bl_h,
                                       W1, b1, W2, b2, W3, b3, W4, b4, Wo, bo,
                                       probs, Mz, cz, Mh, ch, Wc, bc);

    init_kernel<<<(N + 255) / 256, 256, 0, stream>>>(deg, count, N);
    hist_kernel<<<(E + 255) / 256, 256, 0, stream>>>(dstp, ew, deg, count, E);
    scanA_kernel<<<NB, SCAN_B, 0, stream>>>(count, partials, N);
    scanB_kernel<<<1, 64, 0, stream>>>(partials, blockoff, NB);
    scanC_kernel<<<NB, SCAN_B, 0, stream>>>(count, blockoff, rowstart, cursor, deg, N);
    fill_kernel<<<(E + 255) / 256, 256, 0, stream>>>(srcp, dstp, ew, deg, cursor, edges, E);

    gather_node_kernel<<<(N + 3) / 4, 256, 0, stream>>>(x, rowstart, edges, deg,
                                                        probs, Mz, cz, Mh, ch, Wc, bc,
                                                        (float*)d_out, N);
}

// Round 6
// 448.845 us; speedup vs baseline: 2.9911x; 1.2992x over previous
//
#include <hip/hip_runtime.h>
#include <hip/hip_bf16.h>

// Problem constants (shapes fixed by reference)
#define FP 48   // F*P = 4*12 floats per node
#define HID 64
#define NP 12   // periods
#define NF 4    // input feats
#define SCAN_B 1024
#define PL 65   // padded LDS stride for prep tiles

// ---------------------------------------------------------------------------
// prep helpers: register-tiled 64x64 @ 64x64 (A in LDS stride-65, B global)
// ---------------------------------------------------------------------------
__device__ __forceinline__ void mm_stage(const float* __restrict__ Alds,
                                         const float* __restrict__ Wg,
                                         float* __restrict__ Clds, int t)
{
    const int rg = (t >> 4) * 4, cg = (t & 15) * 4;
    float acc[4][4] = {};
    for (int k = 0; k < 64; ++k) {
        float a0 = Alds[(rg + 0) * PL + k];
        float a1 = Alds[(rg + 1) * PL + k];
        float a2 = Alds[(rg + 2) * PL + k];
        float a3 = Alds[(rg + 3) * PL + k];
        const float4 bv = *reinterpret_cast<const float4*>(Wg + k * 64 + cg);
        acc[0][0] += a0 * bv.x; acc[0][1] += a0 * bv.y; acc[0][2] += a0 * bv.z; acc[0][3] += a0 * bv.w;
        acc[1][0] += a1 * bv.x; acc[1][1] += a1 * bv.y; acc[1][2] += a1 * bv.z; acc[1][3] += a1 * bv.w;
        acc[2][0] += a2 * bv.x; acc[2][1] += a2 * bv.y; acc[2][2] += a2 * bv.z; acc[2][3] += a2 * bv.w;
        acc[3][0] += a3 * bv.x; acc[3][1] += a3 * bv.y; acc[3][2] += a3 * bv.z; acc[3][3] += a3 * bv.w;
    }
    for (int i = 0; i < 4; ++i)
        for (int j = 0; j < 4; ++j)
            Clds[(rg + i) * PL + cg + j] = acc[i][j];
}

__device__ __forceinline__ void bias_stage(const float* __restrict__ bin,
                                           const float* __restrict__ Wg,
                                           const float* __restrict__ badd,
                                           float* __restrict__ bout, int t)
{
    if (t < 64) {
        float s = badd[t];
        for (int k = 0; k < 64; ++k) s += bin[k] * Wg[k * 64 + t];
        bout[t] = s;
    }
}

// ---------------------------------------------------------------------------
// prep: probs=softmax(att); Mz=Wg_z@Wl_z[:64]; cz=bg_z@Wl_z[:64]+bl_z (same h);
//       Wc = W1@W2@W3@W4@Wo (64x48); bc = ((((b1@W2+b2)@W3+b3)@W4+b4)@Wo+bo)
// r-gate params provably unused (H=0 => Hz*r = 0).
// ---------------------------------------------------------------------------
__global__ __launch_bounds__(256) void prep_kernel(
    const float* __restrict__ att,
    const float* __restrict__ Wg_z, const float* __restrict__ bg_z,
    const float* __restrict__ Wl_z, const float* __restrict__ bl_z,
    const float* __restrict__ Wg_h, const float* __restrict__ bg_h,
    const float* __restrict__ Wl_h, const float* __restrict__ bl_h,
    const float* __restrict__ W1, const float* __restrict__ b1,
    const float* __restrict__ W2, const float* __restrict__ b2,
    const float* __restrict__ W3, const float* __restrict__ b3,
    const float* __restrict__ W4, const float* __restrict__ b4,
    const float* __restrict__ Wo, const float* __restrict__ bo,
    float* __restrict__ probs, float* __restrict__ Mz, float* __restrict__ cz,
    float* __restrict__ Mh, float* __restrict__ ch,
    float* __restrict__ Wc, float* __restrict__ bc)
{
    __shared__ float A[64 * PL];
    __shared__ float B[64 * PL];
    __shared__ float bias[64];
    __shared__ float bias2[64];
    const int t = threadIdx.x;

    if (t == 0) {
        float m = att[0];
        for (int p = 1; p < NP; ++p) m = fmaxf(m, att[p]);
        float e[NP]; float s = 0.f;
        for (int p = 0; p < NP; ++p) { e[p] = __expf(att[p] - m); s += e[p]; }
        float inv = 1.f / s;
        for (int p = 0; p < NP; ++p) probs[p] = e[p] * inv;
    }

    // gate matrices: Mz/Mh 4x64; thread t -> (f=t>>6, j=t&63)
    {
        int f = t >> 6, j = t & 63;
        float az = 0.f, ah = 0.f;
        for (int k = 0; k < HID; ++k) {
            az += Wg_z[f * HID + k] * Wl_z[k * HID + j];
            ah += Wg_h[f * HID + k] * Wl_h[k * HID + j];
        }
        Mz[t] = az; Mh[t] = ah;
    }
    if (t < HID) {
        float az = bl_z[t], ah = bl_h[t];
        for (int k = 0; k < HID; ++k) {
            az += bg_z[k] * Wl_z[k * HID + t];
            ah += bg_h[k] * Wl_h[k * HID + t];
        }
        cz[t] = az; ch[t] = ah;
    }

    // load W1 -> A (padded)
    for (int idx = t; idx < 4096; idx += 256) {
        int i = idx >> 6, j = idx & 63;
        A[i * PL + j] = W1[idx];
    }
    if (t < 64) bias[t] = b1[t];
    __syncthreads();

    mm_stage(A, W2, B, t);                 // B = W1@W2
    bias_stage(bias, W2, b2, bias2, t);    // bias2 = b1@W2 + b2
    __syncthreads();
    mm_stage(B, W3, A, t);                 // A = (W1W2)@W3
    bias_stage(bias2, W3, b3, bias, t);
    __syncthreads();
    mm_stage(A, W4, B, t);                 // B = (W1W2W3)@W4
    bias_stage(bias, W4, b4, bias2, t);
    __syncthreads();

    // final: Wc = B @ Wo (64x48), bc = bias2@Wo + bo
    {
        const int rg = (t >> 4) * 4, cg = (t & 15) * 4;
        if (cg < FP) {
            float acc[4][4] = {};
            for (int k = 0; k < 64; ++k) {
                float a0 = B[(rg + 0) * PL + k];
                float a1 = B[(rg + 1) * PL + k];
                float a2 = B[(rg + 2) * PL + k];
                float a3 = B[(rg + 3) * PL + k];
                const float4 bv = *reinterpret_cast<const float4*>(Wo + k * FP + cg);
                acc[0][0] += a0 * bv.x; acc[0][1] += a0 * bv.y; acc[0][2] += a0 * bv.z; acc[0][3] += a0 * bv.w;
                acc[1][0] += a1 * bv.x; acc[1][1] += a1 * bv.y; acc[1][2] += a1 * bv.z; acc[1][3] += a1 * bv.w;
                acc[2][0] += a2 * bv.x; acc[2][1] += a2 * bv.y; acc[2][2] += a2 * bv.z; acc[2][3] += a2 * bv.w;
                acc[3][0] += a3 * bv.x; acc[3][1] += a3 * bv.y; acc[3][2] += a3 * bv.z; acc[3][3] += a3 * bv.w;
            }
            for (int i = 0; i < 4; ++i)
                for (int j = 0; j < 4; ++j)
                    Wc[(rg + i) * FP + cg + j] = acc[i][j];
        }
        if (t < FP) {
            float s = bo[t];
            for (int k = 0; k < 64; ++k) s += bias2[k] * Wo[k * FP + t];
            bc[t] = s;
        }
    }
}

// ---------------------------------------------------------------------------
// init: zero the packed histogram and the 16-entry edge pad (kernel, not
// hipMemsetAsync — keeps kernel_launch to pure kernel dispatches for capture)
// ---------------------------------------------------------------------------
__global__ void init_kernel(unsigned long long* __restrict__ packed,
                            int2* __restrict__ edgepad, int N)
{
    int i = blockIdx.x * blockDim.x + threadIdx.x;
    if (i < N) packed[i] = 0ull;
    if (i < 16) edgepad[i] = make_int2(0, 0);
}

// ---------------------------------------------------------------------------
// CSR construction. packed[n] = (count << 40) | fixedpoint24(sum ew)
// max in-degree sum: ~70 * 2^24 << 2^40, so count and weight never collide.
// ---------------------------------------------------------------------------
__global__ void hist_kernel(const int* __restrict__ dst, const float* __restrict__ ew,
                            unsigned long long* __restrict__ packed, int E)
{
    int e = blockIdx.x * blockDim.x + threadIdx.x;
    if (e < E) {
        int d = dst[e];
        unsigned long long v = (1ull << 40) |
            (unsigned long long)(unsigned)__float2uint_rn(ew[e] * 16777216.f);
        atomicAdd(&packed[d], v);
    }
}

// phase A: per-block sums of count
__global__ __launch_bounds__(SCAN_B) void scanA_kernel(const unsigned long long* __restrict__ packed,
                                                       int* __restrict__ partials, int N)
{
    __shared__ int red[SCAN_B];
    const int t = threadIdx.x;
    const int idx = blockIdx.x * SCAN_B + t;
    red[t] = (idx < N) ? (int)(packed[idx] >> 40) : 0;
    __syncthreads();
    for (int s = SCAN_B / 2; s > 0; s >>= 1) {
        if (t < s) red[t] += red[t + s];
        __syncthreads();
    }
    if (t == 0) partials[blockIdx.x] = red[0];
}

// phase B: single-wave exclusive scan of block partials (NB <= 64)
__global__ void scanB_kernel(const int* __restrict__ partials, int* __restrict__ blockoff, int NB)
{
    int l = threadIdx.x;
    int v = (l < NB) ? partials[l] : 0;
    int orig = v;
    for (int off = 1; off < 64; off <<= 1) {
        int u = __shfl_up(v, off, 64);
        if (l >= off) v += u;
    }
    if (l < NB) blockoff[l] = v - orig;
}

// phase C: per-block scan + offset; also computes dinv = rsqrt(1 + sum ew)
__global__ __launch_bounds__(SCAN_B) void scanC_kernel(const unsigned long long* __restrict__ packed,
                                                       const int* __restrict__ blockoff,
                                                       int* __restrict__ rowstart,
                                                       int* __restrict__ cursor,
                                                       float* __restrict__ dinv, int N)
{
    __shared__ int sdata[SCAN_B];
    const int t = threadIdx.x;
    const int idx = blockIdx.x * SCAN_B + t;
    const unsigned long long pk = (idx < N) ? packed[idx] : 0ull;
    const int v = (int)(pk >> 40);
    sdata[t] = v;
    __syncthreads();
    for (int off = 1; off < SCAN_B; off <<= 1) {
        int tmp = (t >= off) ? sdata[t - off] : 0;
        __syncthreads();
        sdata[t] += tmp;
        __syncthreads();
    }
    const int incl = sdata[t];
    const int off0 = blockoff[blockIdx.x];
    if (idx < N) {
        int e = off0 + incl - v;
        rowstart[idx] = e;
        cursor[idx]   = e;
        float deg = 1.0f + (float)(pk & 0xFFFFFFFFFFull) * (1.0f / 16777216.0f);
        dinv[idx] = rsqrtf(deg);   // deg >= 1 always (self loop)
    }
    if (idx == N - 1) rowstart[N] = off0 + incl;
}

// scatter edges into CSR slots; pack {byte offset of src row, w = dinv[src]*ew}
__global__ void fill_kernel(const int* __restrict__ src, const int* __restrict__ dst,
                            const float* __restrict__ ew, const float* __restrict__ dinv,
                            int* __restrict__ cursor, int2* __restrict__ edges, int E)
{
    int e = blockIdx.x * blockDim.x + threadIdx.x;
    if (e < E) {
        int s = src[e], d = dst[e];
        int pos = atomicAdd(&cursor[d], 1);
        int2 pk;
        pk.x = s * (FP * 4);                       // byte offset of x row
        pk.y = __float_as_int(dinv[s] * ew[e]);
        edges[pos] = pk;
    }
}

// ---------------------------------------------------------------------------
// fused gather + node kernel: one wave per dst node.
// lane = slot*16 + q; 4 edge slots, q (clamped to 0..11) loads the slot's x row
// as float4. Branchless inner loop: edges array is padded with 16 zero entries
// so the prefetch load is unguarded (max index end+6 < E+16); weight zeroed by
// cndmask for e>=end. Lanes q in 12..15 compute garbage never read back.
// ---------------------------------------------------------------------------
__global__ __launch_bounds__(256) void gather_node_kernel(
    const float* __restrict__ x, const int* __restrict__ rowstart,
    const int2* __restrict__ edges, const float* __restrict__ dinv,
    const float* __restrict__ probs,
    const float* __restrict__ Mz, const float* __restrict__ cz,
    const float* __restrict__ Mh, const float* __restrict__ ch,
    const float* __restrict__ Wc, const float* __restrict__ bc,
    float* __restrict__ out, int N)
{
    __shared__ float sWc[HID * FP];
    __shared__ float sprobs[NP];
    for (int i = threadIdx.x; i < HID * FP; i += 256) sWc[i] = Wc[i];
    if (threadIdx.x < NP) sprobs[threadIdx.x] = probs[threadIdx.x];
    __syncthreads();

    const int lane = threadIdx.x & 63;
    const int wib  = threadIdx.x >> 6;
    const int n    = blockIdx.x * 4 + wib;
    if (n >= N) return;

    const int q    = lane & 15;
    const int slot = lane >> 4;
    const int qc   = (q < 11) ? q : 11;    // clamped float4 index (lanes 12..15 dup)
    const char* xb = (const char*)x;

    const int beg = rowstart[n];
    const int end = rowstart[n + 1];

    float4 acc = make_float4(0.f, 0.f, 0.f, 0.f);
    {
        int e = beg + slot;
        int2 pk = edges[e];                           // padded: always safe
        float w  = (e < end) ? __int_as_float(pk.y) : 0.f;
        int  off = pk.x;
        #pragma unroll 2
        for (int e0 = beg; e0 < end; e0 += 4) {
            const float wc  = w;
            const int   ofc = off;
            e += 4;
            int2 pk2 = edges[e];                      // prefetch next (padded)
            w   = (e < end) ? __int_as_float(pk2.y) : 0.f;
            off = pk2.x;
            const float4 xv = *reinterpret_cast<const float4*>(xb + ofc + (qc << 4));
            acc.x += wc * xv.x; acc.y += wc * xv.y; acc.z += wc * xv.z; acc.w += wc * xv.w;
        }
    }

    // reduce across the 4 slots
    acc.x += __shfl_xor(acc.x, 16, 64); acc.y += __shfl_xor(acc.y, 16, 64);
    acc.z += __shfl_xor(acc.z, 16, 64); acc.w += __shfl_xor(acc.w, 16, 64);
    acc.x += __shfl_xor(acc.x, 32, 64); acc.y += __shfl_xor(acc.y, 32, 64);
    acc.z += __shfl_xor(acc.z, 32, 64); acc.w += __shfl_xor(acc.w, 32, 64);

    // self loop + symmetric norm
    const float di = dinv[n];
    const float4 xs = *reinterpret_cast<const float4*>(xb + n * (FP * 4) + (qc << 4));
    float4 y4;
    y4.x = di * acc.x + di * di * xs.x;
    y4.y = di * acc.y + di * di * xs.y;
    y4.z = di * acc.z + di * di * xs.z;
    y4.w = di * acc.w + di * di * xs.w;

    // redistribute: lane f (<48) takes component (f&3) of y4 from lane f>>2
    const int srcl = lane >> 2;
    float a0 = __shfl(y4.x, srcl, 64);
    float a1 = __shfl(y4.y, srcl, 64);
    float a2 = __shfl(y4.z, srcl, 64);
    float a3 = __shfl(y4.w, srcl, 64);
    const int r = lane & 3;
    float yv = (r == 0) ? a0 : (r == 1) ? a1 : (r == 2) ? a2 : a3;

    // ---- node phase (lane = hidden dim) ----
    const float mz0 = Mz[lane], mz1 = Mz[64 + lane], mz2 = Mz[128 + lane], mz3 = Mz[192 + lane];
    const float mh0 = Mh[lane], mh1 = Mh[64 + lane], mh2 = Mh[128 + lane], mh3 = Mh[192 + lane];
    const float czv = cz[lane], chv = ch[lane];
    const int   c   = (lane < FP) ? lane : 0;
    const float bcv = bc[c];

    float hacc = 0.f;
    #pragma unroll
    for (int p = 0; p < NP; ++p) {
        float v0 = __shfl(yv, p,      64);
        float v1 = __shfl(yv, p + 12, 64);
        float v2 = __shfl(yv, p + 24, 64);
        float v3 = __shfl(yv, p + 36, 64);
        float az = czv + v0 * mz0 + v1 * mz1 + v2 * mz2 + v3 * mz3;
        float ah = chv + v0 * mh0 + v1 * mh1 + v2 * mh2 + v3 * mh3;
        // (1 - sigmoid(az)) = 1/(1+e^az); tanh(ah) = (e^2ah - 1)/(e^2ah + 1)
        float g  = 1.f / (1.f + __expf(az));
        float ahc = fminf(fmaxf(ah, -15.f), 15.f);
        float eh = __expf(2.f * ahc);
        float th = (eh - 1.f) / (eh + 1.f);
        hacc += sprobs[p] * g * th;
    }
    hacc = fmaxf(hacc, 0.f);

    float o = bcv;
    #pragma unroll 16
    for (int i = 0; i < HID; ++i) {
        float hi = __shfl(hacc, i, 64);
        o += hi * sWc[i * FP + c];
    }
    if (lane < FP) out[(size_t)n * FP + lane] = o;
}

// ---------------------------------------------------------------------------
extern "C" void kernel_launch(void* const* d_in, const int* in_sizes, int n_in,
                              void* d_out, int out_size, void* d_ws, size_t ws_size,
                              hipStream_t stream)
{
    const int N = in_sizes[0] / FP;   // 50000
    const int E = in_sizes[1] / 2;    // 1.6M
    const int NB = (N + SCAN_B - 1) / SCAN_B;

    const float* x    = (const float*)d_in[0];
    const int*   ei   = (const int*)d_in[1];
    const float* ew   = (const float*)d_in[2];
    const float* att  = (const float*)d_in[3];
    const float* Wg_z = (const float*)d_in[4];
    const float* bg_z = (const float*)d_in[5];
    const float* Wl_z = (const float*)d_in[6];
    const float* bl_z = (const float*)d_in[7];
    // d_in[8..11] = r-gate params: unused (H=0 => Hz*r = 0)
    const float* Wg_h = (const float*)d_in[12];
    const float* bg_h = (const float*)d_in[13];
    const float* Wl_h = (const float*)d_in[14];
    const float* bl_h = (const float*)d_in[15];
    const float* W1 = (const float*)d_in[16]; const float* b1 = (const float*)d_in[17];
    const float* W2 = (const float*)d_in[18]; const float* b2 = (const float*)d_in[19];
    const float* W3 = (const float*)d_in[20]; const float* b3 = (const float*)d_in[21];
    const float* W4 = (const float*)d_in[22]; const float* b4 = (const float*)d_in[23];
    const float* Wo = (const float*)d_in[24]; const float* bo = (const float*)d_in[25];

    const int* srcp = ei;
    const int* dstp = ei + E;

    // workspace layout (8B-aligned items first)
    int2*  edges    = (int2*)d_ws;                                       // E + 16 (pad)
    unsigned long long* packed = (unsigned long long*)(edges + E + 16);  // N
    float* dinv     = (float*)(packed + N);                              // N
    int*   rowstart = (int*)(dinv + N);                                  // N+1
    int*   cursor   = rowstart + N + 1;                                  // N
    int*   partials = cursor + N;                                        // 64
    int*   blockoff = partials + 64;                                     // 64
    float* probs    = (float*)(blockoff + 64);                           // 16
    float* Mz       = probs + 16;                                        // 256
    float* cz       = Mz + 256;                                          // 64
    float* Mh       = cz + 64;                                           // 256
    float* ch       = Mh + 256;                                          // 64
    float* Wc       = ch + 64;                                           // 3072
    float* bc       = Wc + HID * FP;                                     // 48

    init_kernel<<<(N + 255) / 256, 256, 0, stream>>>(packed, edges + E, N);

    prep_kernel<<<1, 256, 0, stream>>>(att, Wg_z, bg_z, Wl_z, bl_z, Wg_h, bg_h, Wl_h, bl_h,
                                       W1, b1, W2, b2, W3, b3, W4, b4, Wo, bo,
                                       probs, Mz, cz, Mh, ch, Wc, bc);

    hist_kernel<<<(E + 255) / 256, 256, 0, stream>>>(dstp, ew, packed, E);
    scanA_kernel<<<NB, SCAN_B, 0, stream>>>(packed, partials, N);
    scanB_kernel<<<1, 64, 0, stream>>>(partials, blockoff, NB);
    scanC_kernel<<<NB, SCAN_B, 0, stream>>>(packed, blockoff, rowstart, cursor, dinv, N);
    fill_kernel<<<(E + 255) / 256, 256, 0, stream>>>(srcp, dstp, ew, dinv, cursor, edges, E);

    gather_node_kernel<<<(N + 3) / 4, 256, 0, stream>>>(x, rowstart, edges, dinv,
                                                        probs, Mz, cz, Mh, ch, Wc, bc,
                                                        (float*)d_out, N);
}

// Round 8
// 420.451 us; speedup vs baseline: 3.1931x; 1.0675x over previous
//
#include <hip/hip_runtime.h>
#include <hip/hip_bf16.h>

// Problem constants (shapes fixed by reference)
#define FP 48   // F*P = 4*12 floats per node
#define HID 64
#define NP 12   // periods
#define NF 4    // input feats
#define SCAN_B 1024
#define PL 65   // padded LDS stride for prep tiles

// ---------------------------------------------------------------------------
// prep helpers: register-tiled 64x64 @ 64x64 (A in LDS stride-65, B global)
// ---------------------------------------------------------------------------
__device__ __forceinline__ void mm_stage(const float* __restrict__ Alds,
                                         const float* __restrict__ Wg,
                                         float* __restrict__ Clds, int t)
{
    const int rg = (t >> 4) * 4, cg = (t & 15) * 4;
    float acc[4][4] = {};
    for (int k = 0; k < 64; ++k) {
        float a0 = Alds[(rg + 0) * PL + k];
        float a1 = Alds[(rg + 1) * PL + k];
        float a2 = Alds[(rg + 2) * PL + k];
        float a3 = Alds[(rg + 3) * PL + k];
        const float4 bv = *reinterpret_cast<const float4*>(Wg + k * 64 + cg);
        acc[0][0] += a0 * bv.x; acc[0][1] += a0 * bv.y; acc[0][2] += a0 * bv.z; acc[0][3] += a0 * bv.w;
        acc[1][0] += a1 * bv.x; acc[1][1] += a1 * bv.y; acc[1][2] += a1 * bv.z; acc[1][3] += a1 * bv.w;
        acc[2][0] += a2 * bv.x; acc[2][1] += a2 * bv.y; acc[2][2] += a2 * bv.z; acc[2][3] += a2 * bv.w;
        acc[3][0] += a3 * bv.x; acc[3][1] += a3 * bv.y; acc[3][2] += a3 * bv.z; acc[3][3] += a3 * bv.w;
    }
    for (int i = 0; i < 4; ++i)
        for (int j = 0; j < 4; ++j)
            Clds[(rg + i) * PL + cg + j] = acc[i][j];
}

__device__ __forceinline__ void bias_stage(const float* __restrict__ bin,
                                           const float* __restrict__ Wg,
                                           const float* __restrict__ badd,
                                           float* __restrict__ bout, int t)
{
    if (t < 64) {
        float s = badd[t];
        for (int k = 0; k < 64; ++k) s += bin[k] * Wg[k * 64 + t];
        bout[t] = s;
    }
}

// ---------------------------------------------------------------------------
// fused init + prep: block 0 does the weight-collapse prep; blocks >=1 zero
// the packed histogram and the 16-entry edge pad.
// prep: probs=softmax(att); Mz=Wg_z@Wl_z[:64]; cz=bg_z@Wl_z[:64]+bl_z (same h);
//       Wc = W1@W2@W3@W4@Wo (64x48); bc = ((((b1@W2+b2)@W3+b3)@W4+b4)@Wo+bo)
// r-gate params provably unused (H=0 => Hz*r = 0).
// ---------------------------------------------------------------------------
__global__ __launch_bounds__(256) void init_prep_kernel(
    const float* __restrict__ att,
    const float* __restrict__ Wg_z, const float* __restrict__ bg_z,
    const float* __restrict__ Wl_z, const float* __restrict__ bl_z,
    const float* __restrict__ Wg_h, const float* __restrict__ bg_h,
    const float* __restrict__ Wl_h, const float* __restrict__ bl_h,
    const float* __restrict__ W1, const float* __restrict__ b1,
    const float* __restrict__ W2, const float* __restrict__ b2,
    const float* __restrict__ W3, const float* __restrict__ b3,
    const float* __restrict__ W4, const float* __restrict__ b4,
    const float* __restrict__ Wo, const float* __restrict__ bo,
    float* __restrict__ probs, float* __restrict__ Mz, float* __restrict__ cz,
    float* __restrict__ Mh, float* __restrict__ ch,
    float* __restrict__ Wc, float* __restrict__ bc,
    unsigned long long* __restrict__ packed, int2* __restrict__ edgepad, int N)
{
    const int t = threadIdx.x;

    if (blockIdx.x > 0) {
        int i = (blockIdx.x - 1) * 256 + t;
        if (i < N) packed[i] = 0ull;
        if (blockIdx.x == 1 && t < 16) edgepad[t] = make_int2(0, 0);
        return;
    }

    __shared__ float A[64 * PL];
    __shared__ float B[64 * PL];
    __shared__ float bias[64];
    __shared__ float bias2[64];

    if (t == 0) {
        float m = att[0];
        for (int p = 1; p < NP; ++p) m = fmaxf(m, att[p]);
        float e[NP]; float s = 0.f;
        for (int p = 0; p < NP; ++p) { e[p] = __expf(att[p] - m); s += e[p]; }
        float inv = 1.f / s;
        for (int p = 0; p < NP; ++p) probs[p] = e[p] * inv;
    }

    // gate matrices: Mz/Mh 4x64; thread t -> (f=t>>6, j=t&63)
    {
        int f = t >> 6, j = t & 63;
        float az = 0.f, ah = 0.f;
        for (int k = 0; k < HID; ++k) {
            az += Wg_z[f * HID + k] * Wl_z[k * HID + j];
            ah += Wg_h[f * HID + k] * Wl_h[k * HID + j];
        }
        Mz[t] = az; Mh[t] = ah;
    }
    if (t < HID) {
        float az = bl_z[t], ah = bl_h[t];
        for (int k = 0; k < HID; ++k) {
            az += bg_z[k] * Wl_z[k * HID + t];
            ah += bg_h[k] * Wl_h[k * HID + t];
        }
        cz[t] = az; ch[t] = ah;
    }

    // load W1 -> A (padded)
    for (int idx = t; idx < 4096; idx += 256) {
        int i = idx >> 6, j = idx & 63;
        A[i * PL + j] = W1[idx];
    }
    if (t < 64) bias[t] = b1[t];
    __syncthreads();

    mm_stage(A, W2, B, t);                 // B = W1@W2
    bias_stage(bias, W2, b2, bias2, t);    // bias2 = b1@W2 + b2
    __syncthreads();
    mm_stage(B, W3, A, t);                 // A = (W1W2)@W3
    bias_stage(bias2, W3, b3, bias, t);
    __syncthreads();
    mm_stage(A, W4, B, t);                 // B = (W1W2W3)@W4
    bias_stage(bias, W4, b4, bias2, t);
    __syncthreads();

    // final: Wc = B @ Wo (64x48), bc = bias2@Wo + bo
    {
        const int rg = (t >> 4) * 4, cg = (t & 15) * 4;
        if (cg < FP) {
            float acc[4][4] = {};
            for (int k = 0; k < 64; ++k) {
                float a0 = B[(rg + 0) * PL + k];
                float a1 = B[(rg + 1) * PL + k];
                float a2 = B[(rg + 2) * PL + k];
                float a3 = B[(rg + 3) * PL + k];
                const float4 bv = *reinterpret_cast<const float4*>(Wo + k * FP + cg);
                acc[0][0] += a0 * bv.x; acc[0][1] += a0 * bv.y; acc[0][2] += a0 * bv.z; acc[0][3] += a0 * bv.w;
                acc[1][0] += a1 * bv.x; acc[1][1] += a1 * bv.y; acc[1][2] += a1 * bv.z; acc[1][3] += a1 * bv.w;
                acc[2][0] += a2 * bv.x; acc[2][1] += a2 * bv.y; acc[2][2] += a2 * bv.z; acc[2][3] += a2 * bv.w;
                acc[3][0] += a3 * bv.x; acc[3][1] += a3 * bv.y; acc[3][2] += a3 * bv.z; acc[3][3] += a3 * bv.w;
            }
            for (int i = 0; i < 4; ++i)
                for (int j = 0; j < 4; ++j)
                    Wc[(rg + i) * FP + cg + j] = acc[i][j];
        }
        if (t < FP) {
            float s = bo[t];
            for (int k = 0; k < 64; ++k) s += bias2[k] * Wo[k * FP + t];
            bc[t] = s;
        }
    }
}

// ---------------------------------------------------------------------------
// CSR construction. packed[n] = (count << 40) | fixedpoint24(sum ew)
// count<<40 never collides with the weight bits (sum ew * 2^24 < 2^31 << 2^40).
// ---------------------------------------------------------------------------
__global__ void hist_kernel(const int* __restrict__ dst, const float* __restrict__ ew,
                            unsigned long long* __restrict__ packed, int E)
{
    int e = blockIdx.x * blockDim.x + threadIdx.x;
    if (e < E) {
        int d = dst[e];
        unsigned long long v = (1ull << 40) |
            (unsigned long long)(unsigned)__float2uint_rn(ew[e] * 16777216.f);
        atomicAdd(&packed[d], v);
    }
}

// phase A: per-block sums of count
__global__ __launch_bounds__(SCAN_B) void scanA_kernel(const unsigned long long* __restrict__ packed,
                                                       int* __restrict__ partials, int N)
{
    __shared__ int red[SCAN_B];
    const int t = threadIdx.x;
    const int idx = blockIdx.x * SCAN_B + t;
    red[t] = (idx < N) ? (int)(packed[idx] >> 40) : 0;
    __syncthreads();
    for (int s = SCAN_B / 2; s > 0; s >>= 1) {
        if (t < s) red[t] += red[t + s];
        __syncthreads();
    }
    if (t == 0) partials[blockIdx.x] = red[0];
}

// phase C: per-block scan; block offset computed in-kernel by wave 0 reducing
// partials[0..blockIdx) (NB <= 49 < 64). Fuses dinv = rsqrt(1 + sum ew).
__global__ __launch_bounds__(SCAN_B) void scanC_kernel(const unsigned long long* __restrict__ packed,
                                                       const int* __restrict__ partials,
                                                       int* __restrict__ rowstart,
                                                       int* __restrict__ cursor,
                                                       float* __restrict__ dinv, int N)
{
    __shared__ int sdata[SCAN_B];
    __shared__ int sOff;
    const int t = threadIdx.x;
    const int idx = blockIdx.x * SCAN_B + t;
    const unsigned long long pk = (idx < N) ? packed[idx] : 0ull;
    const int v = (int)(pk >> 40);
    sdata[t] = v;
    if (t < 64) {
        int p = (t < blockIdx.x) ? partials[t] : 0;   // t < blockIdx <= NB-1: in bounds
        for (int m = 1; m < 64; m <<= 1) p += __shfl_xor(p, m, 64);
        if (t == 0) sOff = p;
    }
    __syncthreads();
    for (int off = 1; off < SCAN_B; off <<= 1) {
        int tmp = (t >= off) ? sdata[t - off] : 0;
        __syncthreads();
        sdata[t] += tmp;
        __syncthreads();
    }
    const int incl = sdata[t];
    const int off0 = sOff;
    if (idx < N) {
        int e = off0 + incl - v;
        rowstart[idx] = e;
        cursor[idx]   = e;
        float deg = 1.0f + (float)(pk & 0xFFFFFFFFFFull) * (1.0f / 16777216.0f);
        dinv[idx] = rsqrtf(deg);   // deg >= 1 always (self loop)
    }
    if (idx == N - 1) rowstart[N] = off0 + incl;
}

// scatter edges into CSR slots; pack {byte offset of src row, w = dinv[src]*ew}
__global__ void fill_kernel(const int* __restrict__ src, const int* __restrict__ dst,
                            const float* __restrict__ ew, const float* __restrict__ dinv,
                            int* __restrict__ cursor, int2* __restrict__ edges, int E)
{
    int e = blockIdx.x * blockDim.x + threadIdx.x;
    if (e < E) {
        int s = src[e], d = dst[e];
        int pos = atomicAdd(&cursor[d], 1);
        int2 pk;
        pk.x = s * (FP * 4);                       // byte offset of x row
        pk.y = __float_as_int(dinv[s] * ew[e]);
        edges[pos] = pk;
    }
}

// ---------------------------------------------------------------------------
// fused gather + node kernel: one wave per dst node.
// lane = slot*16 + q; 4 edge slots, q (clamped to 0..11) loads the slot's x row
// as float4. Branchless inner loop (unroll 4 -> up to 4 independent row loads
// in flight per lane): edges array is padded with 16 zero entries so the
// prefetch load is unguarded (max index end+6 < E+16); weight zeroed by
// cndmask for e>=end. Lanes q in 12..15 compute garbage never read back.
// ---------------------------------------------------------------------------
__global__ __launch_bounds__(256) void gather_node_kernel(
    const float* __restrict__ x, const int* __restrict__ rowstart,
    const int2* __restrict__ edges, const float* __restrict__ dinv,
    const float* __restrict__ probs,
    const float* __restrict__ Mz, const float* __restrict__ cz,
    const float* __restrict__ Mh, const float* __restrict__ ch,
    const float* __restrict__ Wc, const float* __restrict__ bc,
    float* __restrict__ out, int N)
{
    __shared__ float sWc[HID * FP];
    __shared__ float sprobs[NP];
    for (int i = threadIdx.x; i < HID * FP; i += 256) sWc[i] = Wc[i];
    if (threadIdx.x < NP) sprobs[threadIdx.x] = probs[threadIdx.x];
    __syncthreads();

    const int lane = threadIdx.x & 63;
    const int wib  = threadIdx.x >> 6;
    const int n    = blockIdx.x * 4 + wib;
    if (n >= N) return;

    const int q    = lane & 15;
    const int slot = lane >> 4;
    const int qc   = (q < 11) ? q : 11;    // clamped float4 index (lanes 12..15 dup)
    const char* xb = (const char*)x;

    const int beg = rowstart[n];
    const int end = rowstart[n + 1];

    float4 acc = make_float4(0.f, 0.f, 0.f, 0.f);
    {
        int e = beg + slot;
        int2 pk = edges[e];                           // padded: always safe
        float w  = (e < end) ? __int_as_float(pk.y) : 0.f;
        int  off = pk.x;
        #pragma unroll 4
        for (int e0 = beg; e0 < end; e0 += 4) {
            const float wc  = w;
            const int   ofc = off;
            e += 4;
            int2 pk2 = edges[e];                      // prefetch next (padded)
            w   = (e < end) ? __int_as_float(pk2.y) : 0.f;
            off = pk2.x;
            const float4 xv = *reinterpret_cast<const float4*>(xb + ofc + (qc << 4));
            acc.x += wc * xv.x; acc.y += wc * xv.y; acc.z += wc * xv.z; acc.w += wc * xv.w;
        }
    }

    // reduce across the 4 slots
    acc.x += __shfl_xor(acc.x, 16, 64); acc.y += __shfl_xor(acc.y, 16, 64);
    acc.z += __shfl_xor(acc.z, 16, 64); acc.w += __shfl_xor(acc.w, 16, 64);
    acc.x += __shfl_xor(acc.x, 32, 64); acc.y += __shfl_xor(acc.y, 32, 64);
    acc.z += __shfl_xor(acc.z, 32, 64); acc.w += __shfl_xor(acc.w, 32, 64);

    // self loop + symmetric norm
    const float di = dinv[n];
    const float4 xs = *reinterpret_cast<const float4*>(xb + n * (FP * 4) + (qc << 4));
    float4 y4;
    y4.x = di * acc.x + di * di * xs.x;
    y4.y = di * acc.y + di * di * xs.y;
    y4.z = di * acc.z + di * di * xs.z;
    y4.w = di * acc.w + di * di * xs.w;

    // redistribute: lane f (<48) takes component (f&3) of y4 from lane f>>2
    const int srcl = lane >> 2;
    float a0 = __shfl(y4.x, srcl, 64);
    float a1 = __shfl(y4.y, srcl, 64);
    float a2 = __shfl(y4.z, srcl, 64);
    float a3 = __shfl(y4.w, srcl, 64);
    const int r = lane & 3;
    float yv = (r == 0) ? a0 : (r == 1) ? a1 : (r == 2) ? a2 : a3;

    // ---- node phase (lane = hidden dim) ----
    const float mz0 = Mz[lane], mz1 = Mz[64 + lane], mz2 = Mz[128 + lane], mz3 = Mz[192 + lane];
    const float mh0 = Mh[lane], mh1 = Mh[64 + lane], mh2 = Mh[128 + lane], mh3 = Mh[192 + lane];
    const float czv = cz[lane], chv = ch[lane];
    const int   c   = (lane < FP) ? lane : 0;
    const float bcv = bc[c];

    float hacc = 0.f;
    #pragma unroll
    for (int p = 0; p < NP; ++p) {
        float v0 = __shfl(yv, p,      64);
        float v1 = __shfl(yv, p + 12, 64);
        float v2 = __shfl(yv, p + 24, 64);
        float v3 = __shfl(yv, p + 36, 64);
        float az = czv + v0 * mz0 + v1 * mz1 + v2 * mz2 + v3 * mz3;
        float ah = chv + v0 * mh0 + v1 * mh1 + v2 * mh2 + v3 * mh3;
        // (1 - sigmoid(az)) = 1/(1+e^az); tanh(ah) = (e^2ah - 1)/(e^2ah + 1)
        float g  = 1.f / (1.f + __expf(az));
        float ahc = fminf(fmaxf(ah, -15.f), 15.f);
        float eh = __expf(2.f * ahc);
        float th = (eh - 1.f) / (eh + 1.f);
        hacc += sprobs[p] * g * th;
    }
    hacc = fmaxf(hacc, 0.f);

    float o = bcv;
    #pragma unroll 16
    for (int i = 0; i < HID; ++i) {
        float hi = __shfl(hacc, i, 64);
        o += hi * sWc[i * FP + c];
    }
    if (lane < FP) out[(size_t)n * FP + lane] = o;
}

// ---------------------------------------------------------------------------
extern "C" void kernel_launch(void* const* d_in, const int* in_sizes, int n_in,
                              void* d_out, int out_size, void* d_ws, size_t ws_size,
                              hipStream_t stream)
{
    const int N = in_sizes[0] / FP;   // 50000
    const int E = in_sizes[1] / 2;    // 1.6M
    const int NB = (N + SCAN_B - 1) / SCAN_B;

    const float* x    = (const float*)d_in[0];
    const int*   ei   = (const int*)d_in[1];
    const float* ew   = (const float*)d_in[2];
    const float* att  = (const float*)d_in[3];
    const float* Wg_z = (const float*)d_in[4];
    const float* bg_z = (const float*)d_in[5];
    const float* Wl_z = (const float*)d_in[6];
    const float* bl_z = (const float*)d_in[7];
    // d_in[8..11] = r-gate params: unused (H=0 => Hz*r = 0)
    const float* Wg_h = (const float*)d_in[12];
    const float* bg_h = (const float*)d_in[13];
    const float* Wl_h = (const float*)d_in[14];
    const float* bl_h = (const float*)d_in[15];
    const float* W1 = (const float*)d_in[16]; const float* b1 = (const float*)d_in[17];
    const float* W2 = (const float*)d_in[18]; const float* b2 = (const float*)d_in[19];
    const float* W3 = (const float*)d_in[20]; const float* b3 = (const float*)d_in[21];
    const float* W4 = (const float*)d_in[22]; const float* b4 = (const float*)d_in[23];
    const float* Wo = (const float*)d_in[24]; const float* bo = (const float*)d_in[25];

    const int* srcp = ei;
    const int* dstp = ei + E;

    // workspace layout (8B-aligned items first) — same footprint as R6 (~14 MB, known-good)
    int2*  edges    = (int2*)d_ws;                                       // E + 16 (pad)
    unsigned long long* packed = (unsigned long long*)(edges + E + 16);  // N
    float* dinv     = (float*)(packed + N);                              // N
    int*   rowstart = (int*)(dinv + N);                                  // N+1
    int*   cursor   = rowstart + N + 1;                                  // N
    int*   partials = cursor + N;                                        // 64
    float* probs    = (float*)(partials + 64);                           // 16
    float* Mz       = probs + 16;                                        // 256
    float* cz       = Mz + 256;                                          // 64
    float* Mh       = cz + 64;                                           // 256
    float* ch       = Mh + 256;                                          // 64
    float* Wc       = ch + 64;                                           // 3072
    float* bc       = Wc + HID * FP;                                     // 48

    const int initBlocks = (N + 255) / 256;
    init_prep_kernel<<<initBlocks + 1, 256, 0, stream>>>(
        att, Wg_z, bg_z, Wl_z, bl_z, Wg_h, bg_h, Wl_h, bl_h,
        W1, b1, W2, b2, W3, b3, W4, b4, Wo, bo,
        probs, Mz, cz, Mh, ch, Wc, bc,
        packed, edges + E, N);

    hist_kernel<<<(E + 255) / 256, 256, 0, stream>>>(dstp, ew, packed, E);
    scanA_kernel<<<NB, SCAN_B, 0, stream>>>(packed, partials, N);
    scanC_kernel<<<NB, SCAN_B, 0, stream>>>(packed, partials, rowstart, cursor, dinv, N);
    fill_kernel<<<(E + 255) / 256, 256, 0, stream>>>(srcp, dstp, ew, dinv, cursor, edges, E);

    gather_node_kernel<<<(N + 3) / 4, 256, 0, stream>>>(x, rowstart, edges, dinv,
                                                        probs, Mz, cz, Mh, ch, Wc, bc,
                                                        (float*)d_out, N);
}

// Round 9
// 387.550 us; speedup vs baseline: 3.4641x; 1.0849x over previous
//
#include <hip/hip_runtime.h>
#include <hip/hip_bf16.h>

// Problem constants (shapes fixed by reference)
#define FP 48   // F*P = 4*12 floats per node
#define HID 64
#define NP 12   // periods
#define NF 4    // input feats
#define SCAN_B 1024
#define PL 65   // padded LDS stride for prep tiles

// ---------------------------------------------------------------------------
// prep helpers: register-tiled 64x64 @ 64x64 (A in LDS stride-65, B global)
// ---------------------------------------------------------------------------
__device__ __forceinline__ void mm_stage(const float* __restrict__ Alds,
                                         const float* __restrict__ Wg,
                                         float* __restrict__ Clds, int t)
{
    const int rg = (t >> 4) * 4, cg = (t & 15) * 4;
    float acc[4][4] = {};
    for (int k = 0; k < 64; ++k) {
        float a0 = Alds[(rg + 0) * PL + k];
        float a1 = Alds[(rg + 1) * PL + k];
        float a2 = Alds[(rg + 2) * PL + k];
        float a3 = Alds[(rg + 3) * PL + k];
        const float4 bv = *reinterpret_cast<const float4*>(Wg + k * 64 + cg);
        acc[0][0] += a0 * bv.x; acc[0][1] += a0 * bv.y; acc[0][2] += a0 * bv.z; acc[0][3] += a0 * bv.w;
        acc[1][0] += a1 * bv.x; acc[1][1] += a1 * bv.y; acc[1][2] += a1 * bv.z; acc[1][3] += a1 * bv.w;
        acc[2][0] += a2 * bv.x; acc[2][1] += a2 * bv.y; acc[2][2] += a2 * bv.z; acc[2][3] += a2 * bv.w;
        acc[3][0] += a3 * bv.x; acc[3][1] += a3 * bv.y; acc[3][2] += a3 * bv.z; acc[3][3] += a3 * bv.w;
    }
    for (int i = 0; i < 4; ++i)
        for (int j = 0; j < 4; ++j)
            Clds[(rg + i) * PL + cg + j] = acc[i][j];
}

__device__ __forceinline__ void bias_stage(const float* __restrict__ bin,
                                           const float* __restrict__ Wg,
                                           const float* __restrict__ badd,
                                           float* __restrict__ bout, int t)
{
    if (t < 64) {
        float s = badd[t];
        for (int k = 0; k < 64; ++k) s += bin[k] * Wg[k * 64 + t];
        bout[t] = s;
    }
}

// ---------------------------------------------------------------------------
// fused init + prep: block 0 does the weight-collapse prep; blocks >=1 zero
// the packed histogram and the 16-entry edge pad.
// prep: probs=softmax(att); Mz=Wg_z@Wl_z[:64]; cz=bg_z@Wl_z[:64]+bl_z (same h);
//       Wc = W1@W2@W3@W4@Wo (64x48); bc = ((((b1@W2+b2)@W3+b3)@W4+b4)@Wo+bo)
// r-gate params provably unused (H=0 => Hz*r = 0).
// ---------------------------------------------------------------------------
__global__ __launch_bounds__(256) void init_prep_kernel(
    const float* __restrict__ att,
    const float* __restrict__ Wg_z, const float* __restrict__ bg_z,
    const float* __restrict__ Wl_z, const float* __restrict__ bl_z,
    const float* __restrict__ Wg_h, const float* __restrict__ bg_h,
    const float* __restrict__ Wl_h, const float* __restrict__ bl_h,
    const float* __restrict__ W1, const float* __restrict__ b1,
    const float* __restrict__ W2, const float* __restrict__ b2,
    const float* __restrict__ W3, const float* __restrict__ b3,
    const float* __restrict__ W4, const float* __restrict__ b4,
    const float* __restrict__ Wo, const float* __restrict__ bo,
    float* __restrict__ probs, float* __restrict__ Mz, float* __restrict__ cz,
    float* __restrict__ Mh, float* __restrict__ ch,
    float* __restrict__ Wc, float* __restrict__ bc,
    unsigned long long* __restrict__ packed, int2* __restrict__ edgepad, int N)
{
    const int t = threadIdx.x;

    if (blockIdx.x > 0) {
        int i = (blockIdx.x - 1) * 256 + t;
        if (i < N) packed[i] = 0ull;
        if (blockIdx.x == 1 && t < 16) edgepad[t] = make_int2(0, 0);
        return;
    }

    __shared__ float A[64 * PL];
    __shared__ float B[64 * PL];
    __shared__ float bias[64];
    __shared__ float bias2[64];

    if (t == 0) {
        float m = att[0];
        for (int p = 1; p < NP; ++p) m = fmaxf(m, att[p]);
        float e[NP]; float s = 0.f;
        for (int p = 0; p < NP; ++p) { e[p] = __expf(att[p] - m); s += e[p]; }
        float inv = 1.f / s;
        for (int p = 0; p < NP; ++p) probs[p] = e[p] * inv;
    }

    // gate matrices: Mz/Mh 4x64; thread t -> (f=t>>6, j=t&63)
    {
        int f = t >> 6, j = t & 63;
        float az = 0.f, ah = 0.f;
        for (int k = 0; k < HID; ++k) {
            az += Wg_z[f * HID + k] * Wl_z[k * HID + j];
            ah += Wg_h[f * HID + k] * Wl_h[k * HID + j];
        }
        Mz[t] = az; Mh[t] = ah;
    }
    if (t < HID) {
        float az = bl_z[t], ah = bl_h[t];
        for (int k = 0; k < HID; ++k) {
            az += bg_z[k] * Wl_z[k * HID + t];
            ah += bg_h[k] * Wl_h[k * HID + t];
        }
        cz[t] = az; ch[t] = ah;
    }

    // load W1 -> A (padded)
    for (int idx = t; idx < 4096; idx += 256) {
        int i = idx >> 6, j = idx & 63;
        A[i * PL + j] = W1[idx];
    }
    if (t < 64) bias[t] = b1[t];
    __syncthreads();

    mm_stage(A, W2, B, t);                 // B = W1@W2
    bias_stage(bias, W2, b2, bias2, t);    // bias2 = b1@W2 + b2
    __syncthreads();
    mm_stage(B, W3, A, t);                 // A = (W1W2)@W3
    bias_stage(bias2, W3, b3, bias, t);
    __syncthreads();
    mm_stage(A, W4, B, t);                 // B = (W1W2W3)@W4
    bias_stage(bias, W4, b4, bias2, t);
    __syncthreads();

    // final: Wc = B @ Wo (64x48), bc = bias2@Wo + bo
    {
        const int rg = (t >> 4) * 4, cg = (t & 15) * 4;
        if (cg < FP) {
            float acc[4][4] = {};
            for (int k = 0; k < 64; ++k) {
                float a0 = B[(rg + 0) * PL + k];
                float a1 = B[(rg + 1) * PL + k];
                float a2 = B[(rg + 2) * PL + k];
                float a3 = B[(rg + 3) * PL + k];
                const float4 bv = *reinterpret_cast<const float4*>(Wo + k * FP + cg);
                acc[0][0] += a0 * bv.x; acc[0][1] += a0 * bv.y; acc[0][2] += a0 * bv.z; acc[0][3] += a0 * bv.w;
                acc[1][0] += a1 * bv.x; acc[1][1] += a1 * bv.y; acc[1][2] += a1 * bv.z; acc[1][3] += a1 * bv.w;
                acc[2][0] += a2 * bv.x; acc[2][1] += a2 * bv.y; acc[2][2] += a2 * bv.z; acc[2][3] += a2 * bv.w;
                acc[3][0] += a3 * bv.x; acc[3][1] += a3 * bv.y; acc[3][2] += a3 * bv.z; acc[3][3] += a3 * bv.w;
            }
            for (int i = 0; i < 4; ++i)
                for (int j = 0; j < 4; ++j)
                    Wc[(rg + i) * FP + cg + j] = acc[i][j];
        }
        if (t < FP) {
            float s = bo[t];
            for (int k = 0; k < 64; ++k) s += bias2[k] * Wo[k * FP + t];
            bc[t] = s;
        }
    }
}

// ---------------------------------------------------------------------------
// CSR construction. packed[n] = (count << 40) | fixedpoint24(sum ew)
// count<<40 never collides with the weight bits (sum ew * 2^24 < 2^31 << 2^40).
// ---------------------------------------------------------------------------
__global__ void hist_kernel(const int* __restrict__ dst, const float* __restrict__ ew,
                            unsigned long long* __restrict__ packed, int E)
{
    int e = blockIdx.x * blockDim.x + threadIdx.x;
    if (e < E) {
        int d = dst[e];
        unsigned long long v = (1ull << 40) |
            (unsigned long long)(unsigned)__float2uint_rn(ew[e] * 16777216.f);
        atomicAdd(&packed[d], v);
    }
}

// phase A: per-block sums of count
__global__ __launch_bounds__(SCAN_B) void scanA_kernel(const unsigned long long* __restrict__ packed,
                                                       int* __restrict__ partials, int N)
{
    __shared__ int red[SCAN_B];
    const int t = threadIdx.x;
    const int idx = blockIdx.x * SCAN_B + t;
    red[t] = (idx < N) ? (int)(packed[idx] >> 40) : 0;
    __syncthreads();
    for (int s = SCAN_B / 2; s > 0; s >>= 1) {
        if (t < s) red[t] += red[t + s];
        __syncthreads();
    }
    if (t == 0) partials[blockIdx.x] = red[0];
}

// phase C: per-block scan; block offset computed in-kernel by wave 0 reducing
// partials[0..blockIdx) (NB <= 49 < 64). Fuses dinv = rsqrt(1 + sum ew).
__global__ __launch_bounds__(SCAN_B) void scanC_kernel(const unsigned long long* __restrict__ packed,
                                                       const int* __restrict__ partials,
                                                       int* __restrict__ rowstart,
                                                       int* __restrict__ cursor,
                                                       float* __restrict__ dinv, int N)
{
    __shared__ int sdata[SCAN_B];
    __shared__ int sOff;
    const int t = threadIdx.x;
    const int idx = blockIdx.x * SCAN_B + t;
    const unsigned long long pk = (idx < N) ? packed[idx] : 0ull;
    const int v = (int)(pk >> 40);
    sdata[t] = v;
    if (t < 64) {
        int p = (t < blockIdx.x) ? partials[t] : 0;   // t < blockIdx <= NB-1: in bounds
        for (int m = 1; m < 64; m <<= 1) p += __shfl_xor(p, m, 64);
        if (t == 0) sOff = p;
    }
    __syncthreads();
    for (int off = 1; off < SCAN_B; off <<= 1) {
        int tmp = (t >= off) ? sdata[t - off] : 0;
        __syncthreads();
        sdata[t] += tmp;
        __syncthreads();
    }
    const int incl = sdata[t];
    const int off0 = sOff;
    if (idx < N) {
        int e = off0 + incl - v;
        rowstart[idx] = e;
        cursor[idx]   = e;
        float deg = 1.0f + (float)(pk & 0xFFFFFFFFFFull) * (1.0f / 16777216.0f);
        dinv[idx] = rsqrtf(deg);   // deg >= 1 always (self loop)
    }
    if (idx == N - 1) rowstart[N] = off0 + incl;
}

// ---------------------------------------------------------------------------
// scatter edges into CSR slots, XCD-affine: grid = 8 * ceil(E/256); a block
// with (blockIdx & 7) == k only writes edges whose dst falls in the k-th
// N/8-range. With round-robin block->XCD placement, each XCD's L2 then
// exclusively owns a ~1.6MB CSR region, so scattered 8B stores merge in L2
// before writeback (vs one RFO+writeback per store across 8 incoherent L2s).
// If the placement heuristic is wrong this degrades to the old behavior.
// ---------------------------------------------------------------------------
__global__ void fill_kernel(const int* __restrict__ src, const int* __restrict__ dst,
                            const float* __restrict__ ew, const float* __restrict__ dinv,
                            int* __restrict__ cursor, int2* __restrict__ edges,
                            int E, int R)
{
    const int xcd   = blockIdx.x & 7;
    const int chunk = blockIdx.x >> 3;
    int e = chunk * 256 + threadIdx.x;
    if (e >= E) return;
    int d = dst[e];
    int lo = xcd * R;
    if (d < lo || d >= lo + R) return;
    int s = src[e];
    int pos = atomicAdd(&cursor[d], 1);
    int2 pk;
    pk.x = s * (FP * 4);                       // byte offset of x row
    pk.y = __float_as_int(dinv[s] * ew[e]);
    edges[pos] = pk;
}

// ---------------------------------------------------------------------------
// fused gather + node kernel: one wave per dst node.
// Gather: lane = slot*16 + q; 4 edge slots, q (clamped to 0..11) loads the
// slot's x row as float4; branchless + prefetch (edges padded by 16 zeros).
// Node phase: per-wave LDS staging replaces shuffle broadcasts —
//   yld[wave][p*4+f] period-major -> 1 ds_read_b128 per period;
//   hld[wave][i]                  -> 16 ds_read_b128 for the head matvec.
// Divisions replaced by v_rcp_f32 (rel err 2.4e-7 << threshold slack).
// ---------------------------------------------------------------------------
__global__ __launch_bounds__(256) void gather_node_kernel(
    const float* __restrict__ x, const int* __restrict__ rowstart,
    const int2* __restrict__ edges, const float* __restrict__ dinv,
    const float* __restrict__ probs,
    const float* __restrict__ Mz, const float* __restrict__ cz,
    const float* __restrict__ Mh, const float* __restrict__ ch,
    const float* __restrict__ Wc, const float* __restrict__ bc,
    float* __restrict__ out, int N)
{
    __shared__ __align__(16) float sWc[HID * FP];
    __shared__ __align__(16) float sprobs[16];
    __shared__ __align__(16) float yld[4][FP];   // per-wave, period-major (p*4+f)
    __shared__ __align__(16) float hld[4][HID];  // per-wave hidden vector
    for (int i = threadIdx.x; i < HID * FP; i += 256) sWc[i] = Wc[i];
    if (threadIdx.x < NP) sprobs[threadIdx.x] = probs[threadIdx.x];
    __syncthreads();

    const int lane = threadIdx.x & 63;
    const int wib  = threadIdx.x >> 6;
    const int n    = blockIdx.x * 4 + wib;
    if (n >= N) return;

    const int q    = lane & 15;
    const int slot = lane >> 4;
    const int qc   = (q < 11) ? q : 11;    // clamped float4 index (lanes 12..15 dup)
    const char* xb = (const char*)x;

    const int beg = rowstart[n];
    const int end = rowstart[n + 1];

    float4 acc = make_float4(0.f, 0.f, 0.f, 0.f);
    {
        int e = beg + slot;
        int2 pk = edges[e];                           // padded: always safe
        float w  = (e < end) ? __int_as_float(pk.y) : 0.f;
        int  off = pk.x;
        #pragma unroll 4
        for (int e0 = beg; e0 < end; e0 += 4) {
            const float wc  = w;
            const int   ofc = off;
            e += 4;
            int2 pk2 = edges[e];                      // prefetch next (padded)
            w   = (e < end) ? __int_as_float(pk2.y) : 0.f;
            off = pk2.x;
            const float4 xv = *reinterpret_cast<const float4*>(xb + ofc + (qc << 4));
            acc.x += wc * xv.x; acc.y += wc * xv.y; acc.z += wc * xv.z; acc.w += wc * xv.w;
        }
    }

    // reduce across the 4 slots
    acc.x += __shfl_xor(acc.x, 16, 64); acc.y += __shfl_xor(acc.y, 16, 64);
    acc.z += __shfl_xor(acc.z, 16, 64); acc.w += __shfl_xor(acc.w, 16, 64);
    acc.x += __shfl_xor(acc.x, 32, 64); acc.y += __shfl_xor(acc.y, 32, 64);
    acc.z += __shfl_xor(acc.z, 32, 64); acc.w += __shfl_xor(acc.w, 32, 64);

    // self loop + symmetric norm
    const float di = dinv[n];
    const float4 xs = *reinterpret_cast<const float4*>(xb + n * (FP * 4) + (qc << 4));
    float4 y4;
    y4.x = di * acc.x + di * di * xs.x;
    y4.y = di * acc.y + di * di * xs.y;
    y4.z = di * acc.z + di * di * xs.z;
    y4.w = di * acc.w + di * di * xs.w;

    // redistribute: lane l (<48) takes component (l&3) of y4 from lane l>>2;
    // lane l corresponds to (feat f = l/12, period p = l%12) of the x row.
    const int srcl = lane >> 2;
    float a0 = __shfl(y4.x, srcl, 64);
    float a1 = __shfl(y4.y, srcl, 64);
    float a2 = __shfl(y4.z, srcl, 64);
    float a3 = __shfl(y4.w, srcl, 64);
    const int r = lane & 3;
    float yv = (r == 0) ? a0 : (r == 1) ? a1 : (r == 2) ? a2 : a3;

    // stash into per-wave LDS, period-major: yld[wib][p*4 + f]
    if (lane < FP) {
        int f = lane / 12;
        int p = lane - f * 12;
        yld[wib][p * 4 + f] = yv;
    }

    // ---- node phase (lane = hidden dim) ----
    const float mz0 = Mz[lane], mz1 = Mz[64 + lane], mz2 = Mz[128 + lane], mz3 = Mz[192 + lane];
    const float mh0 = Mh[lane], mh1 = Mh[64 + lane], mh2 = Mh[128 + lane], mh3 = Mh[192 + lane];
    const float czv = cz[lane], chv = ch[lane];
    const int   c   = (lane < FP) ? lane : 0;
    const float bcv = bc[c];

    const float* yw = yld[wib];
    float hacc = 0.f;
    #pragma unroll
    for (int p = 0; p < NP; ++p) {
        const float4 v = *reinterpret_cast<const float4*>(yw + p * 4);  // broadcast b128
        float az = czv + v.x * mz0 + v.y * mz1 + v.z * mz2 + v.w * mz3;
        float ah = chv + v.x * mh0 + v.y * mh1 + v.z * mh2 + v.w * mh3;
        // (1 - sigmoid(az)) = rcp(1+e^az)   (e^az -> inf => rcp -> 0, graceful)
        float g  = __builtin_amdgcn_rcpf(1.f + __expf(az));
        // tanh(ah) = 1 - 2*rcp(e^{2ah}+1), clamp to keep e^{2ah} finite
        float ahc = fminf(fmaxf(ah, -15.f), 15.f);
        float eh = __expf(2.f * ahc);
        float th = 1.f - 2.f * __builtin_amdgcn_rcpf(eh + 1.f);
        hacc += sprobs[p] * g * th;
    }
    hacc = fmaxf(hacc, 0.f);

    hld[wib][lane] = hacc;
    const float* hw = hld[wib];
    float o = bcv;
    #pragma unroll
    for (int i4 = 0; i4 < 16; ++i4) {
        const float4 h4 = *reinterpret_cast<const float4*>(hw + i4 * 4); // broadcast b128
        o += h4.x * sWc[(i4 * 4 + 0) * FP + c];
        o += h4.y * sWc[(i4 * 4 + 1) * FP + c];
        o += h4.z * sWc[(i4 * 4 + 2) * FP + c];
        o += h4.w * sWc[(i4 * 4 + 3) * FP + c];
    }
    if (lane < FP) out[(size_t)n * FP + lane] = o;
}

// ---------------------------------------------------------------------------
extern "C" void kernel_launch(void* const* d_in, const int* in_sizes, int n_in,
                              void* d_out, int out_size, void* d_ws, size_t ws_size,
                              hipStream_t stream)
{
    const int N = in_sizes[0] / FP;   // 50000
    const int E = in_sizes[1] / 2;    // 1.6M
    const int NB = (N + SCAN_B - 1) / SCAN_B;

    const float* x    = (const float*)d_in[0];
    const int*   ei   = (const int*)d_in[1];
    const float* ew   = (const float*)d_in[2];
    const float* att  = (const float*)d_in[3];
    const float* Wg_z = (const float*)d_in[4];
    const float* bg_z = (const float*)d_in[5];
    const float* Wl_z = (const float*)d_in[6];
    const float* bl_z = (const float*)d_in[7];
    // d_in[8..11] = r-gate params: unused (H=0 => Hz*r = 0)
    const float* Wg_h = (const float*)d_in[12];
    const float* bg_h = (const float*)d_in[13];
    const float* Wl_h = (const float*)d_in[14];
    const float* bl_h = (const float*)d_in[15];
    const float* W1 = (const float*)d_in[16]; const float* b1 = (const float*)d_in[17];
    const float* W2 = (const float*)d_in[18]; const float* b2 = (const float*)d_in[19];
    const float* W3 = (const float*)d_in[20]; const float* b3 = (const float*)d_in[21];
    const float* W4 = (const float*)d_in[22]; const float* b4 = (const float*)d_in[23];
    const float* Wo = (const float*)d_in[24]; const float* bo = (const float*)d_in[25];

    const int* srcp = ei;
    const int* dstp = ei + E;

    // workspace layout (8B-aligned items first) — same footprint as R6/R8 (~14 MB, known-good)
    int2*  edges    = (int2*)d_ws;                                       // E + 16 (pad)
    unsigned long long* packed = (unsigned long long*)(edges + E + 16);  // N
    float* dinv     = (float*)(packed + N);                              // N
    int*   rowstart = (int*)(dinv + N);                                  // N+1
    int*   cursor   = rowstart + N + 1;                                  // N
    int*   partials = cursor + N;                                        // 64
    float* probs    = (float*)(partials + 64);                           // 16
    float* Mz       = probs + 16;                                        // 256
    float* cz       = Mz + 256;                                          // 64
    float* Mh       = cz + 64;                                           // 256
    float* ch       = Mh + 256;                                          // 64
    float* Wc       = ch + 64;                                           // 3072
    float* bc       = Wc + HID * FP;                                     // 48

    const int initBlocks = (N + 255) / 256;
    init_prep_kernel<<<initBlocks + 1, 256, 0, stream>>>(
        att, Wg_z, bg_z, Wl_z, bl_z, Wg_h, bg_h, Wl_h, bl_h,
        W1, b1, W2, b2, W3, b3, W4, b4, Wo, bo,
        probs, Mz, cz, Mh, ch, Wc, bc,
        packed, edges + E, N);

    hist_kernel<<<(E + 255) / 256, 256, 0, stream>>>(dstp, ew, packed, E);
    scanA_kernel<<<NB, SCAN_B, 0, stream>>>(packed, partials, N);
    scanC_kernel<<<NB, SCAN_B, 0, stream>>>(packed, partials, rowstart, cursor, dinv, N);

    const int R = (N + 7) / 8;                          // dst-range per XCD bin
    const int chunks = (E + 255) / 256;
    fill_kernel<<<chunks * 8, 256, 0, stream>>>(srcp, dstp, ew, dinv, cursor, edges, E, R);

    gather_node_kernel<<<(N + 3) / 4, 256, 0, stream>>>(x, rowstart, edges, dinv,
                                                        probs, Mz, cz, Mh, ch, Wc, bc,
                                                        (float*)d_out, N);
}

// Round 10
// 348.049 us; speedup vs baseline: 3.8573x; 1.1135x over previous
//
#include <hip/hip_runtime.h>
#include <hip/hip_bf16.h>

// Problem constants (shapes fixed by reference)
#define FP 48   // F*P = 4*12 floats per node
#define HID 64
#define NP 12   // periods
#define NF 4    // input feats
#define SCAN_B 1024
#define PL 65   // padded LDS stride for prep tiles

// ---------------------------------------------------------------------------
// prep helpers: register-tiled 64x64 @ 64x64 (A in LDS stride-65, B global)
// ---------------------------------------------------------------------------
__device__ __forceinline__ void mm_stage(const float* __restrict__ Alds,
                                         const float* __restrict__ Wg,
                                         float* __restrict__ Clds, int t)
{
    const int rg = (t >> 4) * 4, cg = (t & 15) * 4;
    float acc[4][4] = {};
    for (int k = 0; k < 64; ++k) {
        float a0 = Alds[(rg + 0) * PL + k];
        float a1 = Alds[(rg + 1) * PL + k];
        float a2 = Alds[(rg + 2) * PL + k];
        float a3 = Alds[(rg + 3) * PL + k];
        const float4 bv = *reinterpret_cast<const float4*>(Wg + k * 64 + cg);
        acc[0][0] += a0 * bv.x; acc[0][1] += a0 * bv.y; acc[0][2] += a0 * bv.z; acc[0][3] += a0 * bv.w;
        acc[1][0] += a1 * bv.x; acc[1][1] += a1 * bv.y; acc[1][2] += a1 * bv.z; acc[1][3] += a1 * bv.w;
        acc[2][0] += a2 * bv.x; acc[2][1] += a2 * bv.y; acc[2][2] += a2 * bv.z; acc[2][3] += a2 * bv.w;
        acc[3][0] += a3 * bv.x; acc[3][1] += a3 * bv.y; acc[3][2] += a3 * bv.z; acc[3][3] += a3 * bv.w;
    }
    for (int i = 0; i < 4; ++i)
        for (int j = 0; j < 4; ++j)
            Clds[(rg + i) * PL + cg + j] = acc[i][j];
}

__device__ __forceinline__ void bias_stage(const float* __restrict__ bin,
                                           const float* __restrict__ Wg,
                                           const float* __restrict__ badd,
                                           float* __restrict__ bout, int t)
{
    if (t < 64) {
        float s = badd[t];
        for (int k = 0; k < 64; ++k) s += bin[k] * Wg[k * 64 + t];
        bout[t] = s;
    }
}

// ---------------------------------------------------------------------------
// fused init + prep: block 0 does the weight-collapse prep; blocks >=1 zero
// the packed histogram and the 16-entry edge pad.
// r-gate params provably unused (H=0 => Hz*r = 0).
// ---------------------------------------------------------------------------
__global__ __launch_bounds__(256) void init_prep_kernel(
    const float* __restrict__ att,
    const float* __restrict__ Wg_z, const float* __restrict__ bg_z,
    const float* __restrict__ Wl_z, const float* __restrict__ bl_z,
    const float* __restrict__ Wg_h, const float* __restrict__ bg_h,
    const float* __restrict__ Wl_h, const float* __restrict__ bl_h,
    const float* __restrict__ W1, const float* __restrict__ b1,
    const float* __restrict__ W2, const float* __restrict__ b2,
    const float* __restrict__ W3, const float* __restrict__ b3,
    const float* __restrict__ W4, const float* __restrict__ b4,
    const float* __restrict__ Wo, const float* __restrict__ bo,
    float* __restrict__ probs, float* __restrict__ Mz, float* __restrict__ cz,
    float* __restrict__ Mh, float* __restrict__ ch,
    float* __restrict__ Wc, float* __restrict__ bc,
    unsigned long long* __restrict__ packed, int2* __restrict__ edgepad, int N)
{
    const int t = threadIdx.x;

    if (blockIdx.x > 0) {
        int i = (blockIdx.x - 1) * 256 + t;
        if (i < N) packed[i] = 0ull;
        if (blockIdx.x == 1 && t < 16) edgepad[t] = make_int2(0, 0);
        return;
    }

    __shared__ float A[64 * PL];
    __shared__ float B[64 * PL];
    __shared__ float bias[64];
    __shared__ float bias2[64];

    if (t == 0) {
        float m = att[0];
        for (int p = 1; p < NP; ++p) m = fmaxf(m, att[p]);
        float e[NP]; float s = 0.f;
        for (int p = 0; p < NP; ++p) { e[p] = __expf(att[p] - m); s += e[p]; }
        float inv = 1.f / s;
        for (int p = 0; p < NP; ++p) probs[p] = e[p] * inv;
    }

    // gate matrices: Mz/Mh 4x64; thread t -> (f=t>>6, j=t&63)
    {
        int f = t >> 6, j = t & 63;
        float az = 0.f, ah = 0.f;
        for (int k = 0; k < HID; ++k) {
            az += Wg_z[f * HID + k] * Wl_z[k * HID + j];
            ah += Wg_h[f * HID + k] * Wl_h[k * HID + j];
        }
        Mz[t] = az; Mh[t] = ah;
    }
    if (t < HID) {
        float az = bl_z[t], ah = bl_h[t];
        for (int k = 0; k < HID; ++k) {
            az += bg_z[k] * Wl_z[k * HID + t];
            ah += bg_h[k] * Wl_h[k * HID + t];
        }
        cz[t] = az; ch[t] = ah;
    }

    // load W1 -> A (padded)
    for (int idx = t; idx < 4096; idx += 256) {
        int i = idx >> 6, j = idx & 63;
        A[i * PL + j] = W1[idx];
    }
    if (t < 64) bias[t] = b1[t];
    __syncthreads();

    mm_stage(A, W2, B, t);                 // B = W1@W2
    bias_stage(bias, W2, b2, bias2, t);    // bias2 = b1@W2 + b2
    __syncthreads();
    mm_stage(B, W3, A, t);                 // A = (W1W2)@W3
    bias_stage(bias2, W3, b3, bias, t);
    __syncthreads();
    mm_stage(A, W4, B, t);                 // B = (W1W2W3)@W4
    bias_stage(bias, W4, b4, bias2, t);
    __syncthreads();

    // final: Wc = B @ Wo (64x48), bc = bias2@Wo + bo
    {
        const int rg = (t >> 4) * 4, cg = (t & 15) * 4;
        if (cg < FP) {
            float acc[4][4] = {};
            for (int k = 0; k < 64; ++k) {
                float a0 = B[(rg + 0) * PL + k];
                float a1 = B[(rg + 1) * PL + k];
                float a2 = B[(rg + 2) * PL + k];
                float a3 = B[(rg + 3) * PL + k];
                const float4 bv = *reinterpret_cast<const float4*>(Wo + k * FP + cg);
                acc[0][0] += a0 * bv.x; acc[0][1] += a0 * bv.y; acc[0][2] += a0 * bv.z; acc[0][3] += a0 * bv.w;
                acc[1][0] += a1 * bv.x; acc[1][1] += a1 * bv.y; acc[1][2] += a1 * bv.z; acc[1][3] += a1 * bv.w;
                acc[2][0] += a2 * bv.x; acc[2][1] += a2 * bv.y; acc[2][2] += a2 * bv.z; acc[2][3] += a2 * bv.w;
                acc[3][0] += a3 * bv.x; acc[3][1] += a3 * bv.y; acc[3][2] += a3 * bv.z; acc[3][3] += a3 * bv.w;
            }
            for (int i = 0; i < 4; ++i)
                for (int j = 0; j < 4; ++j)
                    Wc[(rg + i) * FP + cg + j] = acc[i][j];
        }
        if (t < FP) {
            float s = bo[t];
            for (int k = 0; k < 64; ++k) s += bias2[k] * Wo[k * FP + t];
            bc[t] = s;
        }
    }
}

// ---------------------------------------------------------------------------
// CSR construction. packed[n] = (count << 40) | fixedpoint24(sum ew).
// The atomic's RETURN value yields this edge's rank among same-dst edges
// (old count = bits >= 40) -> stored coalesced so fill needs NO atomic.
// count<<40 never collides with weight bits (sum ew * 2^24 < 2^31 << 2^40).
// ---------------------------------------------------------------------------
__global__ void hist_kernel(const int* __restrict__ dst, const float* __restrict__ ew,
                            unsigned long long* __restrict__ packed,
                            int* __restrict__ rank, int E)
{
    int e = blockIdx.x * blockDim.x + threadIdx.x;
    if (e < E) {
        int d = dst[e];
        unsigned long long v = (1ull << 40) |
            (unsigned long long)(unsigned)__float2uint_rn(ew[e] * 16777216.f);
        unsigned long long old = atomicAdd(&packed[d], v);
        rank[e] = (int)(old >> 40);
    }
}

// phase A: per-block sums of count
__global__ __launch_bounds__(SCAN_B) void scanA_kernel(const unsigned long long* __restrict__ packed,
                                                       int* __restrict__ partials, int N)
{
    __shared__ int red[SCAN_B];
    const int t = threadIdx.x;
    const int idx = blockIdx.x * SCAN_B + t;
    red[t] = (idx < N) ? (int)(packed[idx] >> 40) : 0;
    __syncthreads();
    for (int s = SCAN_B / 2; s > 0; s >>= 1) {
        if (t < s) red[t] += red[t + s];
        __syncthreads();
    }
    if (t == 0) partials[blockIdx.x] = red[0];
}

// phase C: per-block scan; block offset computed in-kernel by wave 0 reducing
// partials[0..blockIdx) (NB <= 49 < 64). Fuses dinv = rsqrt(1 + sum ew).
__global__ __launch_bounds__(SCAN_B) void scanC_kernel(const unsigned long long* __restrict__ packed,
                                                       const int* __restrict__ partials,
                                                       int* __restrict__ rowstart,
                                                       float* __restrict__ dinv, int N)
{
    __shared__ int sdata[SCAN_B];
    __shared__ int sOff;
    const int t = threadIdx.x;
    const int idx = blockIdx.x * SCAN_B + t;
    const unsigned long long pk = (idx < N) ? packed[idx] : 0ull;
    const int v = (int)(pk >> 40);
    sdata[t] = v;
    if (t < 64) {
        int p = (t < blockIdx.x) ? partials[t] : 0;   // t < blockIdx <= NB-1: in bounds
        for (int m = 1; m < 64; m <<= 1) p += __shfl_xor(p, m, 64);
        if (t == 0) sOff = p;
    }
    __syncthreads();
    for (int off = 1; off < SCAN_B; off <<= 1) {
        int tmp = (t >= off) ? sdata[t - off] : 0;
        __syncthreads();
        sdata[t] += tmp;
        __syncthreads();
    }
    const int incl = sdata[t];
    const int off0 = sOff;
    if (idx < N) {
        int e = off0 + incl - v;
        rowstart[idx] = e;
        float deg = 1.0f + (float)(pk & 0xFFFFFFFFFFull) * (1.0f / 16777216.0f);
        dinv[idx] = rsqrtf(deg);   // deg >= 1 always (self loop)
    }
    if (idx == N - 1) rowstart[N] = off0 + incl;
}

// ---------------------------------------------------------------------------
// scatter edges into CSR slots — atomic-free: pos = rowstart[dst] + rank[e].
// XCD-affine: grid = 8 * ceil(E/256); block (blockIdx & 7)==k only writes
// edges whose dst falls in the k-th N/8-range, so each XCD's L2 owns a ~1.6MB
// CSR region and the scattered 8B stores merge in L2 before writeback.
// ---------------------------------------------------------------------------
__global__ void fill_kernel(const int* __restrict__ src, const int* __restrict__ dst,
                            const float* __restrict__ ew, const float* __restrict__ dinv,
                            const int* __restrict__ rowstart, const int* __restrict__ rank,
                            int2* __restrict__ edges, int E, int R)
{
    const int xcd   = blockIdx.x & 7;
    const int chunk = blockIdx.x >> 3;
    int e = chunk * 256 + threadIdx.x;
    if (e >= E) return;
    int d = dst[e];
    int lo = xcd * R;
    if (d < lo || d >= lo + R) return;
    int s = src[e];
    int pos = rowstart[d] + rank[e];
    int2 pk;
    pk.x = s * (FP * 4);                       // byte offset of x row
    pk.y = __float_as_int(dinv[s] * ew[e]);
    edges[pos] = pk;
}

// ---------------------------------------------------------------------------
// fused gather + node kernel: one wave per dst node.
// Gather: 5 edge slots x 12 lanes (slot = lane/12, q = lane%12); each slot's
// 12 lanes load its x row as float4 (48 floats exactly) — all loads useful.
// Lanes 60..63 idle (w=0). Branchless + prefetch (edges padded by 16 zeros;
// max index < E+16). Cross-slot reduce via per-wave LDS scratch (write f4 at
// s*48+4q; lane l sums yacc[s*48+l], stride-48 reads are conflict-free),
// which also replaces the old shuffle redistribute. Node phase: LDS b128
// broadcasts (yld period-major, hld) + rcp-based gates (rel err ~2e-7).
// ---------------------------------------------------------------------------
__global__ __launch_bounds__(256) void gather_node_kernel(
    const float* __restrict__ x, const int* __restrict__ rowstart,
    const int2* __restrict__ edges, const float* __restrict__ dinv,
    const float* __restrict__ probs,
    const float* __restrict__ Mz, const float* __restrict__ cz,
    const float* __restrict__ Mh, const float* __restrict__ ch,
    const float* __restrict__ Wc, const float* __restrict__ bc,
    float* __restrict__ out, int N)
{
    __shared__ __align__(16) float sWc[HID * FP];
    __shared__ __align__(16) float sprobs[16];
    __shared__ __align__(16) float yacc[4][240];  // per-wave 5-slot partials (5*48)
    __shared__ __align__(16) float yld[4][FP];    // per-wave, period-major (p*4+f)
    __shared__ __align__(16) float hld[4][HID];   // per-wave hidden vector
    for (int i = threadIdx.x; i < HID * FP; i += 256) sWc[i] = Wc[i];
    if (threadIdx.x < NP) sprobs[threadIdx.x] = probs[threadIdx.x];
    __syncthreads();

    const int lane = threadIdx.x & 63;
    const int wib  = threadIdx.x >> 6;
    const int n    = blockIdx.x * 4 + wib;
    if (n >= N) return;

    const int slot = lane / 12;            // 0..4 active, 5 = idle lanes 60..63
    const int q    = lane - slot * 12;     // float4 index within row, 0..11
    const bool act = (slot < 5);
    const char* xb = (const char*)x;

    const int beg = rowstart[n];
    const int end = rowstart[n + 1];

    float4 acc = make_float4(0.f, 0.f, 0.f, 0.f);
    {
        int e = beg + slot;
        int2 pk = edges[e];                           // padded: always safe
        float w  = (act && e < end) ? __int_as_float(pk.y) : 0.f;
        int  off = pk.x;
        #pragma unroll 4
        for (int e0 = beg; e0 < end; e0 += 5) {
            const float wc  = w;
            const int   ofc = off;
            e += 5;
            int2 pk2 = edges[e];                      // prefetch next (padded)
            w   = (act && e < end) ? __int_as_float(pk2.y) : 0.f;
            off = pk2.x;
            const float4 xv = *reinterpret_cast<const float4*>(xb + ofc + (q << 4));
            acc.x += wc * xv.x; acc.y += wc * xv.y; acc.z += wc * xv.z; acc.w += wc * xv.w;
        }
    }

    // reduce across the 5 slots via per-wave LDS
    if (act)
        *reinterpret_cast<float4*>(&yacc[wib][slot * 48 + q * 4]) = acc;

    // lane l (<48) owns row float l: sum 5 slot partials, add self-loop, norm
    const float di = dinv[n];
    if (lane < FP) {
        const float* yf = yacc[wib];
        float s = yf[lane] + yf[48 + lane] + yf[96 + lane] + yf[144 + lane] + yf[192 + lane];
        float xself = x[(size_t)n * FP + lane];
        float yv = di * s + di * di * xself;
        int f = lane / 12;
        int p = lane - f * 12;
        yld[wib][p * 4 + f] = yv;          // period-major stash
    }

    // ---- node phase (lane = hidden dim) ----
    const float mz0 = Mz[lane], mz1 = Mz[64 + lane], mz2 = Mz[128 + lane], mz3 = Mz[192 + lane];
    const float mh0 = Mh[lane], mh1 = Mh[64 + lane], mh2 = Mh[128 + lane], mh3 = Mh[192 + lane];
    const float czv = cz[lane], chv = ch[lane];
    const int   c   = (lane < FP) ? lane : 0;
    const float bcv = bc[c];

    const float* yw = yld[wib];
    float hacc = 0.f;
    #pragma unroll
    for (int p = 0; p < NP; ++p) {
        const float4 v = *reinterpret_cast<const float4*>(yw + p * 4);  // broadcast b128
        float az = czv + v.x * mz0 + v.y * mz1 + v.z * mz2 + v.w * mz3;
        float ah = chv + v.x * mh0 + v.y * mh1 + v.z * mh2 + v.w * mh3;
        // (1 - sigmoid(az)) = rcp(1+e^az)   (e^az -> inf => rcp -> 0, graceful)
        float g  = __builtin_amdgcn_rcpf(1.f + __expf(az));
        // tanh(ah) = 1 - 2*rcp(e^{2ah}+1), clamp to keep e^{2ah} finite
        float ahc = fminf(fmaxf(ah, -15.f), 15.f);
        float eh = __expf(2.f * ahc);
        float th = 1.f - 2.f * __builtin_amdgcn_rcpf(eh + 1.f);
        hacc += sprobs[p] * g * th;
    }
    hacc = fmaxf(hacc, 0.f);

    hld[wib][lane] = hacc;
    const float* hw = hld[wib];
    float o = bcv;
    #pragma unroll
    for (int i4 = 0; i4 < 16; ++i4) {
        const float4 h4 = *reinterpret_cast<const float4*>(hw + i4 * 4); // broadcast b128
        o += h4.x * sWc[(i4 * 4 + 0) * FP + c];
        o += h4.y * sWc[(i4 * 4 + 1) * FP + c];
        o += h4.z * sWc[(i4 * 4 + 2) * FP + c];
        o += h4.w * sWc[(i4 * 4 + 3) * FP + c];
    }
    if (lane < FP) out[(size_t)n * FP + lane] = o;
}

// ---------------------------------------------------------------------------
extern "C" void kernel_launch(void* const* d_in, const int* in_sizes, int n_in,
                              void* d_out, int out_size, void* d_ws, size_t ws_size,
                              hipStream_t stream)
{
    const int N = in_sizes[0] / FP;   // 50000
    const int E = in_sizes[1] / 2;    // 1.6M
    const int NB = (N + SCAN_B - 1) / SCAN_B;

    const float* x    = (const float*)d_in[0];
    const int*   ei   = (const int*)d_in[1];
    const float* ew   = (const float*)d_in[2];
    const float* att  = (const float*)d_in[3];
    const float* Wg_z = (const float*)d_in[4];
    const float* bg_z = (const float*)d_in[5];
    const float* Wl_z = (const float*)d_in[6];
    const float* bl_z = (const float*)d_in[7];
    // d_in[8..11] = r-gate params: unused (H=0 => Hz*r = 0)
    const float* Wg_h = (const float*)d_in[12];
    const float* bg_h = (const float*)d_in[13];
    const float* Wl_h = (const float*)d_in[14];
    const float* bl_h = (const float*)d_in[15];
    const float* W1 = (const float*)d_in[16]; const float* b1 = (const float*)d_in[17];
    const float* W2 = (const float*)d_in[18]; const float* b2 = (const float*)d_in[19];
    const float* W3 = (const float*)d_in[20]; const float* b3 = (const float*)d_in[21];
    const float* W4 = (const float*)d_in[22]; const float* b4 = (const float*)d_in[23];
    const float* Wo = (const float*)d_in[24]; const float* bo = (const float*)d_in[25];

    const int* srcp = ei;
    const int* dstp = ei + E;

    // workspace layout (8B-aligned items first) — ~20.5 MB of 256 MiB ws
    int2*  edges    = (int2*)d_ws;                                       // E + 16 (pad)
    unsigned long long* packed = (unsigned long long*)(edges + E + 16);  // N
    int*   rank     = (int*)(packed + N);                                // E
    float* dinv     = (float*)(rank + E);                                // N
    int*   rowstart = (int*)(dinv + N);                                  // N+1
    int*   partials = rowstart + N + 1;                                  // 64
    float* probs    = (float*)(partials + 64);                           // 16
    float* Mz       = probs + 16;                                        // 256
    float* cz       = Mz + 256;                                          // 64
    float* Mh       = cz + 64;                                           // 256
    float* ch       = Mh + 256;                                          // 64
    float* Wc       = ch + 64;                                           // 3072
    float* bc       = Wc + HID * FP;                                     // 48

    const int initBlocks = (N + 255) / 256;
    init_prep_kernel<<<initBlocks + 1, 256, 0, stream>>>(
        att, Wg_z, bg_z, Wl_z, bl_z, Wg_h, bg_h, Wl_h, bl_h,
        W1, b1, W2, b2, W3, b3, W4, b4, Wo, bo,
        probs, Mz, cz, Mh, ch, Wc, bc,
        packed, edges + E, N);

    hist_kernel<<<(E + 255) / 256, 256, 0, stream>>>(dstp, ew, packed, rank, E);
    scanA_kernel<<<NB, SCAN_B, 0, stream>>>(packed, partials, N);
    scanC_kernel<<<NB, SCAN_B, 0, stream>>>(packed, partials, rowstart, dinv, N);

    const int R = (N + 7) / 8;                          // dst-range per XCD bin
    const int chunks = (E + 255) / 256;
    fill_kernel<<<chunks * 8, 256, 0, stream>>>(srcp, dstp, ew, dinv, rowstart, rank, edges, E, R);

    gather_node_kernel<<<(N + 3) / 4, 256, 0, stream>>>(x, rowstart, edges, dinv,
                                                        probs, Mz, cz, Mh, ch, Wc, bc,
                                                        (float*)d_out, N);
}